// Round 4
// baseline (1687.604 us; speedup 1.0000x reference)
//
#include <hip/hip_runtime.h>
#include <hip/hip_fp16.h>
#include <math.h>

#define TID ((int)threadIdx.x)

// dims: V=30000 K=50 E=300 T=60 B=128 TH=800 H=200 L=3
// mf2 tiling: NVB=235 v-blocks of 128 rows; mega-mf1: NVB2=79 v-blocks of 384 rows
#define NVB 235
#define NVB2 79

// flag indices
#define FG_S01   0
#define FG_S12   32
#define FG_S23   64
#define FG_S34   96
#define FG_S45   128
#define FG_ETAT  160
#define FG_MF1D  192
#define FG_H1D   196
#define FG_H1ED  200
#define FG_H2D   204
#define FG_MULSD 208
#define FG_MF2D  212

static __device__ __forceinline__ float sigf(float x){ return 1.f/(1.f+__expf(-x)); }
static __device__ __forceinline__ float tanhfast(float x){
  float t = fminf(fmaxf(x,-15.f),15.f);
  float e = __expf(2.f*t);
  return (e-1.f)/(e+1.f);
}

static __device__ __forceinline__ unsigned short f2bf(float f){
  unsigned u = __float_as_uint(f);
  unsigned r = (u + 0x7FFFu + ((u>>16)&1u)) >> 16;
  return (unsigned short)r;
}

typedef short v8ss __attribute__((ext_vector_type(8)));
typedef float v16f __attribute__((ext_vector_type(16)));
union I4BF { int4 i; v8ss s; };
union U16B { int4 i; __half2 h2[4]; };

#define REP25(M) M(0) M(1) M(2) M(3) M(4) M(5) M(6) M(7) M(8) M(9) M(10) M(11) \
                 M(12) M(13) M(14) M(15) M(16) M(17) M(18) M(19) M(20) M(21) M(22) M(23) M(24)

// inline f32 -> f16 weight row fragment (8 cols) into named int4 reg
#define DECLWF(n) int4 w##n; { float4 fA = rowF[2*(n)], fB = rowF[2*(n)+1]; U16B u; \
    u.h2[0]=__floats2half2_rn(fA.x,fA.y); u.h2[1]=__floats2half2_rn(fA.z,fA.w); \
    u.h2[2]=__floats2half2_rn(fB.x,fB.y); u.h2[3]=__floats2half2_rn(fB.z,fB.w); w##n=u.i; }

#define DOTW(n) { U16B u; u.i = w##n; \
    float4 hA = hs4[2*(n)], hB = hs4[2*(n)+1]; \
    float2 q0=__half22float2(u.h2[0]), q1=__half22float2(u.h2[1]); \
    float2 q2=__half22float2(u.h2[2]), q3=__half22float2(u.h2[3]); \
    a0=fmaf(q0.x,hA.x,a0); a1=fmaf(q0.y,hA.y,a1); \
    a2=fmaf(q1.x,hA.z,a2); a3=fmaf(q1.y,hA.w,a3); \
    a0=fmaf(q2.x,hB.x,a0); a1=fmaf(q2.y,hB.y,a1); \
    a2=fmaf(q3.x,hB.z,a2); a3=fmaf(q3.y,hB.w,a3); }

// ---------------- init ----------------
__global__ void k_zero(float* acc, int* flags){
  if (TID<8) acc[TID]=0.f;
  if (TID<256) flags[TID]=0;
}

// ---------------- alphas + kl_alpha (merged; recompute prev alpha) ----------------
__global__ void k_alphakl(const float* __restrict__ mqa, const float* __restrict__ lqa,
                          const float* __restrict__ eps, float* __restrict__ alphas,
                          float* acc){
  __shared__ float red[256];
  int i = blockIdx.x*256+TID;
  float term = 0.f;
  if (i<900000){
    int t = i/15000, r = i%15000, k = r/300, e = r%300;
    int src = k*18000 + t*300 + e;
    float mu = mqa[src], ls = lqa[src];
    alphas[i] = mu + eps[i]*__expf(0.5f*ls);
    if (t==0){
      term = (__expf(ls)+mu*mu)*(1.0f/(1.0f+1e-6f)) - 1.f - ls;
    } else {
      int sp = src - 300;
      float mup = mqa[sp], lsp = lqa[sp];
      float ap = mup + eps[i-15000]*__expf(0.5f*lsp);
      float d = mu - ap;
      term = (__expf(ls)+d*d)*(1.0f/(0.005f+1e-6f)) - 1.f + logf(0.005f) - ls;
    }
  }
  red[TID]=term; __syncthreads();
  for (int s=128;s>0;s>>=1){ if (TID<s) red[TID]+=red[TID+s]; __syncthreads(); }
  if (TID==0) atomicAdd(acc+0, 0.5f*red[0]);
}

// ---------------- bf16 fragment prep for alpha ----------------
__global__ void k_prep_alpha(const float* __restrict__ alphas, unsigned short* __restrict__ alpha_f){
  int tid = blockIdx.x*256+TID;
  if (tid >= 60*2*19*64) return;
  int lane = tid & 63;
  int F = tid >> 6;
  int kstep = F % 19;
  int tn = F / 19;
  int nt = tn % 2, t = tn / 2;
  int k = nt*32 + (lane & 31);
  int e0 = kstep*16 + ((lane>>5)<<3);
  unsigned short u[8];
  #pragma unroll
  for (int j=0;j<8;j++){
    int e = e0 + j;
    float val = (k < 50 && e < 300) ? alphas[t*15000 + k*300 + e] : 0.f;
    u[j] = f2bf(val);
  }
  int4 o;
  o.x = (int)u[0] | ((int)u[1]<<16);
  o.y = (int)u[2] | ((int)u[3]<<16);
  o.z = (int)u[4] | ((int)u[5]<<16);
  o.w = (int)u[6] | ((int)u[7]<<16);
  ((int4*)alpha_f)[tid] = o;
}

// ---------------- inp_map = rnn_inp @ Wmap.T + bmap ----------------
__global__ void k_iminit(float* __restrict__ im, const float* __restrict__ bmap){
  int i = blockIdx.x*256+TID; if (i<12000) im[i] = bmap[i%200];
}

__global__ __launch_bounds__(256,2) void k_imgemm(const float* __restrict__ rnn,
        const float* __restrict__ Wmap, float* __restrict__ im){
  __shared__ __align__(16) float Ws[32*500];
  __shared__ __align__(16) float rnS[500];
  int hb = blockIdx.x;       // 0..6
  int kb = blockIdx.y;       // 0..59
  int h0 = hb*32;
  int nh = (h0+32<=200)?32:(200-h0);
  const int kbase = kb*500;
  for (int i=TID; i<nh*125; i+=256){
    int h = i/125, q = i%125;
    *reinterpret_cast<float4*>(&Ws[h*500 + q*4]) =
      *reinterpret_cast<const float4*>(&Wmap[(h0+h)*30000 + kbase + q*4]);
  }
  int h = TID>>3, sub = TID&7;
  bool act = (h < nh);
  __syncthreads();
  for (int t=0;t<60;t++){
    if (TID<125)
      *reinterpret_cast<float4*>(&rnS[TID*4]) =
        *reinterpret_cast<const float4*>(&rnn[t*30000 + kbase + TID*4]);
    __syncthreads();
    float a = 0.f;
    if (act){
      const float2* wp = reinterpret_cast<const float2*>(&Ws[h*500]);
      const float2* rp = reinterpret_cast<const float2*>(rnS);
      for (int k2=sub;k2<250;k2+=8){
        float2 wv=wp[k2], rv=rp[k2];
        a = fmaf(wv.x,rv.x,a); a = fmaf(wv.y,rv.y,a);
      }
    }
    a += __shfl_down(a,4); a += __shfl_down(a,2); a += __shfl_down(a,1);
    if (act && sub==0) atomicAdd(&im[t*200 + h0 + h], a);
    __syncthreads();
  }
}

// ---------------- LSTM pre-gates (layer 0 only; input fully known) ----------------
__global__ void k_pregates(const float* __restrict__ x, const float* __restrict__ Wih,
                           const float* __restrict__ bih, const float* __restrict__ bhh,
                           float* __restrict__ pre){
  __shared__ float xS[200];
  int t = blockIdx.x;
  if (TID<200) xS[TID] = x[t*200+TID];
  __syncthreads();
  int r = blockIdx.y*256 + TID;
  if (r>=800) return;
  float a = bih[r] + bhh[r];
  const float* wp = Wih + r*200;
  #pragma unroll 4
  for (int c=0;c<200;c++) a = fmaf(wp[c], xS[c], a);
  pre[t*800+r] = a;
}

// ================= MEGA KERNEL =================
// blocks 0-5: LSTM pipe (rec0,gemv1,rec1,gemv2,rec2,eta)
// 6-163: mf1 (79 vb x 2 tg, with self-prep of rho fragments)
// 164-323: h1 main GEMM
// 324-335: msred   336-351: h1eta   352-369: h2   370-391: muls   392-402: theta
// All <=403 blocks co-resident (2 blocks/CU at 53KB LDS) => spin-waits deadlock-free.

template<int SLP>
static __device__ __forceinline__ void pipe_wait(int* flag, int val){
  if (TID==0){
    while (__hip_atomic_load(flag, __ATOMIC_RELAXED, __HIP_MEMORY_SCOPE_AGENT) < val)
      __builtin_amdgcn_s_sleep(SLP);
    (void)__hip_atomic_load(flag, __ATOMIC_ACQUIRE, __HIP_MEMORY_SCOPE_AGENT);
  }
  __syncthreads();
}

static __device__ __forceinline__ void pipe_post(int* flag, int val){
  // caller guarantees __syncthreads() (vmcnt drained) precedes this
  if (TID==0)
    __hip_atomic_store(flag, val, __ATOMIC_RELEASE, __HIP_MEMORY_SCOPE_AGENT);
}

static __device__ __forceinline__ void post_done(int* ctr){
  __syncthreads();
  if (TID==0)
    __hip_atomic_fetch_add(ctr, 1, __ATOMIC_RELEASE, __HIP_MEMORY_SCOPE_AGENT);
}

// recurrent cell chain: weights f32->f16 inline into 25 named int4 regs
static __device__ void lstm_rec(char* sm, const float* __restrict__ pre,
    const float* __restrict__ WhhF, float* __restrict__ out,
    int* inFlag, int* outFlag)
{
  float* hsF = (float*)sm;              // 200 f
  float* gsh = (float*)(sm + 800);      // 800 f
  __half* wtH = (__half*)(sm + 4000);   // 6400 h
  for (int i=TID;i<6400;i+=768) wtH[i] = __float2half_rn(WhhF[768*200 + i]);
  const float4* rowF = reinterpret_cast<const float4*>(WhhF + TID*200);
  REP25(DECLWF)
  float c_reg = 0.f;
  if (TID<200) hsF[TID]=0.f;
  int j = TID - 512;
  int trow = (j>=0) ? (j>>3) : 0;
  int tseg = (j>=0) ? (j&7)*25 : 0;
  __syncthreads();
  for (int t=0;t<60;t++){
    if (inFlag) pipe_wait<1>(inFlag, t+1);
    float p = pre[t*800+TID];          // latency hides under the h-dot below
    float a0=0.f,a1=0.f,a2=0.f,a3=0.f;
    const float4* hs4 = reinterpret_cast<const float4*>(hsF);
    REP25(DOTW)
    gsh[TID] = a0+a1+a2+a3 + p;
    if (j>=0){
      float pa = 0.f;
      const __half* wt = &wtH[trow*200 + tseg];
      const float* hp = &hsF[tseg];
      #pragma unroll
      for (int c2=0;c2<25;c2++) pa = fmaf(__half2float(wt[c2]), hp[c2], pa);
      pa += __shfl_down(pa,4); pa += __shfl_down(pa,2); pa += __shfl_down(pa,1);
      if ((j&7)==0) gsh[768+trow] = pa + pre[t*800+768+trow];
    }
    __syncthreads();
    if (TID<200){
      float ii=gsh[TID], ff=gsh[200+TID], gg=gsh[400+TID], oo=gsh[600+TID];
      float c = sigf(ff)*c_reg + sigf(ii)*tanhfast(gg);
      c_reg = c;
      float h = sigf(oo)*tanhfast(c);
      hsF[TID]=h;
      out[t*200+TID]=h;
    }
    __syncthreads();
    if (outFlag) pipe_post(outFlag, t+1);
  }
}

// input-gemv stage: pre_l[t] = Wih_l @ out_{l-1}[t] + bih + bhh
static __device__ void lstm_gemv(char* sm, const float* __restrict__ xIn,
    const float* __restrict__ WF, const float* __restrict__ bih,
    const float* __restrict__ bhh, float* __restrict__ preOut,
    int* inFlag, int* outFlag)
{
  float* xS = (float*)sm;               // 200 f
  __half* wtG = (__half*)(sm + 800);    // 6400 h
  for (int i=TID;i<6400;i+=768) wtG[i] = __float2half_rn(WF[768*200 + i]);
  const float4* rowF = reinterpret_cast<const float4*>(WF + TID*200);
  REP25(DECLWF)
  float bb = bih[TID] + bhh[TID];
  int j = TID - 512;
  int trow = (j>=0) ? (j>>3) : 0;
  int tseg = (j>=0) ? (j&7)*25 : 0;
  float bbT = 0.f;
  if (j>=0 && (j&7)==0) bbT = bih[768+trow] + bhh[768+trow];
  for (int t=0;t<60;t++){
    pipe_wait<1>(inFlag, t+1);
    if (TID<200) xS[TID] = xIn[t*200+TID];
    __syncthreads();
    float a0=0.f,a1=0.f,a2=0.f,a3=0.f;
    const float4* hs4 = reinterpret_cast<const float4*>(xS);
    REP25(DOTW)
    preOut[t*800+TID] = a0+a1+a2+a3 + bb;
    if (j>=0){
      float pa = 0.f;
      const __half* wt = &wtG[trow*200 + tseg];
      const float* hp = &xS[tseg];
      #pragma unroll
      for (int c2=0;c2<25;c2++) pa = fmaf(__half2float(wt[c2]), hp[c2], pa);
      pa += __shfl_down(pa,4); pa += __shfl_down(pa,2); pa += __shfl_down(pa,1);
      if ((j&7)==0) preOut[t*800+768+trow] = pa + bbT;
    }
    __syncthreads();
    pipe_post(outFlag, t+1);
  }
}

// eta chain as 6th pipeline stage; posts per-t flag for h1eta consumers
static __device__ void eta_stage(char* sm, const float* __restrict__ outF,
    const float* __restrict__ Wmu, const float* __restrict__ bmu,
    const float* __restrict__ Wls, const float* __restrict__ bls,
    const float* __restrict__ eps, float* __restrict__ etas, float* acc,
    int* inFlag, int* etaT)
{
  __half* wS = (__half*)sm;                 // 100*254 h = 50800 B
  float* inp = (float*)(sm + 50816);        // 256 f
  float* pt  = (float*)(sm + 51840);        // 200 f
  float* muS = (float*)(sm + 52640);        // 64 f
  float* lsS = (float*)(sm + 52896);        // 64 f
  for (int i=TID;i<12500;i+=768) wS[(i/250)*254 + (i%250)] = __float2half_rn(Wmu[i]);
  for (int i=TID;i<12500;i+=768) wS[(50+i/250)*254 + (i%250)] = __float2half_rn(Wls[i]);
  if (TID<50) inp[200+TID]=0.f;
  const float LOGD = logf(0.005f);
  float kacc = 0.f;
  __syncthreads();
  for (int t=0;t<60;t++){
    pipe_wait<1>(inFlag, t+1);
    if (TID<200) inp[TID] = outF[t*200+TID];
    __syncthreads();
    if (TID<200){
      int rr = TID%100, hf = TID/100;
      const __half* wp = &wS[rr*254 + hf*125];
      const float* ip = &inp[hf*125];
      float s=0.f;
      for (int c=0;c<125;c++) s = fmaf(__half2float(wp[c]), ip[c], s);
      pt[TID]=s;
    }
    __syncthreads();
    if (TID<100){
      float v = pt[TID]+pt[TID+100];
      if (TID<50) muS[TID] = v + bmu[TID];
      else lsS[TID-50] = v + bls[TID-50];
    }
    __syncthreads();
    if (TID<64){
      float term=0.f;
      if (TID<50){
        float mu=muS[TID], ls=lsS[TID], ep=inp[200+TID];
        if (t==0) term = (__expf(ls)+mu*mu)*(1.0f/(1.0f+1e-6f)) - 1.f - ls;
        else { float d=mu-ep; term = (__expf(ls)+d*d)*(1.0f/(0.005f+1e-6f)) - 1.f + LOGD - ls; }
        float et = mu + eps[t*50+TID]*__expf(0.5f*ls);
        etas[t*50+TID]=et;
        inp[200+TID]=et;
      }
      for (int o=32;o>0;o>>=1) term += __shfl_down(term,o);
      if (TID==0) kacc += 0.5f*term;
    }
    __syncthreads();
    pipe_post(etaT, t+1);
  }
  if (TID==0) atomicAdd(acc+1, kacc);
}

// MFMA beta pass 1, self-prepping rho fragments: 12 waves = 384 v-rows per block
static __device__ void mf1_block(char* sm, int vb, int tg,
    const float* __restrict__ rho,
    unsigned short* __restrict__ rho_f, const unsigned short* __restrict__ alpha_f,
    float* __restrict__ Mp, float* __restrict__ Sp, int* mf1d)
{
  // prep this block's 12 rho fragment rows (tg twins duplicate: identical values)
  for (int i=TID; i<12*19*64; i+=768){
    int lane2 = i & 63;
    int F = i >> 6;
    int kstep = F % 19;
    int rr = F / 19;
    int r32p = vb*12 + rr;
    if (r32p >= 940) continue;
    int v = r32p*32 + (lane2 & 31);
    int e0 = kstep*16 + ((lane2>>5)<<3);
    unsigned short u[8];
    #pragma unroll
    for (int jj=0;jj<8;jj++){
      int e = e0 + jj;
      float val = (v < 30000 && e < 300) ? rho[v*300 + e] : 0.f;
      u[jj] = f2bf(val);
    }
    int4 o;
    o.x = (int)u[0] | ((int)u[1]<<16);
    o.y = (int)u[2] | ((int)u[3]<<16);
    o.z = (int)u[4] | ((int)u[5]<<16);
    o.w = (int)u[6] | ((int)u[7]<<16);
    ((int4*)rho_f)[(r32p*19 + kstep)*64 + lane2] = o;
  }
  __syncthreads();
  float* redM = (float*)sm;            // 12*64 f
  float* redS = (float*)(sm + 3072);   // 12*64 f
  int wid = TID>>6, lane = TID&63;
  int r32 = vb*12 + wid;
  bool valid = (r32 < 940);
  int4 zi; zi.x=0; zi.y=0; zi.z=0; zi.w=0;
  const int4* ap = ((const int4*)rho_f) + (r32*19)*64 + lane;
  int4 a[19];
  #pragma unroll
  for (int ks=0;ks<19;ks++) a[ks] = valid ? ap[ks*64] : zi;
  int rowbase = vb*384 + wid*32 + ((lane>>5)<<2);
  for (int t = tg*30; t < tg*30+30; t++){
    v16f acc0, acc1;
    #pragma unroll
    for (int i=0;i<16;i++){ acc0[i]=0.f; acc1[i]=0.f; }
    const int4* bp = ((const int4*)alpha_f) + (t*38)*64 + lane;
    #pragma unroll
    for (int ks=0;ks<19;ks++){
      I4BF av, b0, b1;
      av.i = a[ks];
      b0.i = bp[ks*64];
      b1.i = bp[(19+ks)*64];
      acc0 = __builtin_amdgcn_mfma_f32_32x32x16_bf16(av.s, b0.s, acc0, 0,0,0);
      acc1 = __builtin_amdgcn_mfma_f32_32x32x16_bf16(av.s, b1.s, acc1, 0,0,0);
    }
    float m0=-INFINITY, m1=-INFINITY;
    #pragma unroll
    for (int r=0;r<16;r++){
      int v = rowbase + (r&3) + ((r>>2)<<3);
      if (v < 30000){ m0 = fmaxf(m0, acc0[r]); m1 = fmaxf(m1, acc1[r]); }
    }
    m0 = fmaxf(m0, __shfl_xor(m0, 32));
    m1 = fmaxf(m1, __shfl_xor(m1, 32));
    float s0=0.f, s1=0.f;
    #pragma unroll
    for (int r=0;r<16;r++){
      int v = rowbase + (r&3) + ((r>>2)<<3);
      if (v < 30000){ s0 += __expf(acc0[r]-m0); s1 += __expf(acc1[r]-m1); }
    }
    s0 += __shfl_xor(s0, 32);
    s1 += __shfl_xor(s1, 32);
    if (lane < 32){
      redM[wid*64+lane] = m0; redM[wid*64+lane+32] = m1;
      redS[wid*64+lane] = s0; redS[wid*64+lane+32] = s1;
    }
    __syncthreads();
    if (TID < 50){
      float M = redM[TID];
      #pragma unroll
      for (int w2=1; w2<12; w2++) M = fmaxf(M, redM[w2*64+TID]);
      float S = 0.f;
      #pragma unroll
      for (int w2=0; w2<12; w2++){
        float mw = redM[w2*64+TID];
        if (mw > -INFINITY) S += redS[w2*64+TID] * __expf(mw - M);
      }
      Mp[(t*50+TID)*NVB2 + vb] = M;
      Sp[(t*50+TID)*NVB2 + vb] = S;
    }
    __syncthreads();
  }
  post_done(mf1d);
}

// h1 main GEMM (k<30000 only): 3 rt-tiles share one A-tile
static __device__ void h1_block(char* sm, int rtg, int sp,
    const float* __restrict__ nb, const float* __restrict__ W1,
    float* __restrict__ h1, int* h1d)
{
  float* As = (float*)sm;               // 16*132 f
  float* WsAll = (float*)(sm + 8448);   // 3 * 16*68 f
  int sub = TID>>8, l = TID&255;
  int rt = rtg*3 + sub;                 // 0..14 (rows >=800 masked)
  float* Ws = WsAll + sub*(16*68);
  int kbeg = sp*940;
  int kend = kbeg+940; if (kend>30000) kend=30000;
  int b0 = (l%32)*4, r0 = (l/32)*8;
  float acc[32];
  #pragma unroll
  for (int jj=0;jj<32;jj++) acc[jj]=0.f;
  for (int kb=kbeg; kb<kend; kb+=16){
    __syncthreads();
    for (int i=TID;i<2048;i+=768){
      int b=i>>4, kk=i&15, kg=kb+kk;
      As[kk*132+b] = (kg<kend) ? nb[b*30000+kg] : 0.f;
    }
    for (int i=l;i<1024;i+=256){
      int r=i>>4, kk=i&15, kg=kb+kk, rg=rt*64+r;
      Ws[kk*68+r] = (kg<kend && rg<800) ? W1[rg*30050+kg] : 0.f;
    }
    __syncthreads();
    #pragma unroll
    for (int kk=0;kk<16;kk++){
      float4 a4 = *reinterpret_cast<const float4*>(&As[kk*132+b0]);
      float4 w4 = *reinterpret_cast<const float4*>(&Ws[kk*68+r0]);
      float4 w5 = *reinterpret_cast<const float4*>(&Ws[kk*68+r0+4]);
      float aa[4]={a4.x,a4.y,a4.z,a4.w};
      float ww[8]={w4.x,w4.y,w4.z,w4.w,w5.x,w5.y,w5.z,w5.w};
      #pragma unroll
      for (int j=0;j<4;j++)
        #pragma unroll
        for (int i2=0;i2<8;i2++) acc[j*8+i2] = fmaf(aa[j], ww[i2], acc[j*8+i2]);
    }
  }
  #pragma unroll
  for (int j=0;j<4;j++){
    int b=b0+j;
    #pragma unroll
    for (int i2=0;i2<8;i2++){
      int rg = rt*64+r0+i2;
      if (rg<800) atomicAdd(&h1[b*800+rg], acc[j*8+i2]);
    }
  }
  post_done(h1d);
}

// reduce Mp/Sp partials -> Mg, 1/S  (12 blocks x 12 waves; wave per row)
static __device__ void msred_role(int blk, const float* __restrict__ Mp,
    const float* __restrict__ Sp, float* __restrict__ Mg, float* __restrict__ iSg,
    int* mf1d)
{
  pipe_wait<16>(mf1d, 158);
  int w = TID>>6, lane = TID&63;
  for (int row = blk*12 + w; row < 3000; row += 144){
    float m0 = (lane < NVB2) ? Mp[row*NVB2 + lane] : -INFINITY;
    float m1 = (64+lane < NVB2) ? Mp[row*NVB2 + 64 + lane] : -INFINITY;
    float s0 = (lane < NVB2) ? Sp[row*NVB2 + lane] : 0.f;
    float s1 = (64+lane < NVB2) ? Sp[row*NVB2 + 64 + lane] : 0.f;
    float mm = fmaxf(m0, m1);
    for (int o=32;o>0;o>>=1) mm = fmaxf(mm, __shfl_xor(mm,o));
    float e = 0.f;
    if (m0 > -INFINITY) e += s0*__expf(m0-mm);
    if (m1 > -INFINITY) e += s1*__expf(m1-mm);
    for (int o=32;o>0;o>>=1) e += __shfl_xor(e,o);
    if (lane==0){ Mg[row]=mm; iSg[row]=1.f/e; }
  }
}

// eta columns of h1 + bias (per-doc overlap with eta pipeline)
static __device__ void h1eta_role(char* sm, int blk, const float* __restrict__ etas,
    const int* __restrict__ times, const float* __restrict__ W1,
    const float* __restrict__ b1, float* __restrict__ h1, int* etaT, int* h1ed)
{
  float* eS = (float*)sm;  // 64 f
  for (int d=0; d<8; d++){
    int b = blk*8 + d;
    int tb = times[b];
    pipe_wait<4>(etaT, tb+1);
    if (TID<50) eS[TID] = etas[tb*50+TID];
    __syncthreads();
    for (int r=TID; r<800; r+=768){
      const float* wp = W1 + r*30050 + 30000;
      float a2 = b1[r];
      #pragma unroll 10
      for (int c=0;c<50;c++) a2 = fmaf(wp[c], eS[c], a2);
      atomicAdd(&h1[b*800+r], a2);
    }
    __syncthreads();
  }
  post_done(h1ed);
}

// h2 = relu(relu(h1) @ W2.T + b2): 3 tiles of 32docs x 64rows per block
static __device__ void h2_role(char* sm, int blk, const float* __restrict__ h1,
    const float* __restrict__ W2, const float* __restrict__ b2,
    float* __restrict__ h2, int* h1d, int* h1ed, int* h2d)
{
  pipe_wait<16>(h1d, 160);
  pipe_wait<16>(h1ed, 16);
  int sub = TID>>8, l = TID&255;
  int tile = blk*3 + sub;            // 0..53, valid <52
  bool tv = (tile < 52);
  int bt = tile/13, rt = tile%13;
  float* As = (float*)sm + sub*(16*33);
  float* Ws = (float*)(sm + 3*16*33*4) + sub*(16*68);
  int b0 = (l%16)*2, r0 = (l/16)*4;
  float acc[8] = {0,0,0,0,0,0,0,0};
  for (int kb=0; kb<800; kb+=16){
    __syncthreads();
    if (tv){
      for (int i=l;i<512;i+=256){
        int b=i>>4, k=i&15;
        As[k*33+b] = fmaxf(h1[(bt*32+b)*800 + kb + k], 0.f);
      }
      for (int i=l;i<1024;i+=256){
        int r=i>>4, k=i&15; int rg = rt*64+r;
        Ws[k*68+r] = (rg<800) ? W2[rg*800 + kb + k] : 0.f;
      }
    }
    __syncthreads();
    if (tv){
      #pragma unroll
      for (int k=0;k<16;k++){
        float a0=As[k*33+b0], a1=As[k*33+b0+1];
        float4 w4 = *reinterpret_cast<const float4*>(&Ws[k*68+r0]);
        acc[0]=fmaf(a0,w4.x,acc[0]); acc[1]=fmaf(a0,w4.y,acc[1]);
        acc[2]=fmaf(a0,w4.z,acc[2]); acc[3]=fmaf(a0,w4.w,acc[3]);
        acc[4]=fmaf(a1,w4.x,acc[4]); acc[5]=fmaf(a1,w4.y,acc[5]);
        acc[6]=fmaf(a1,w4.z,acc[6]); acc[7]=fmaf(a1,w4.w,acc[7]);
      }
    }
  }
  if (tv){
    #pragma unroll
    for (int jj=0;jj<2;jj++){
      int b = bt*32 + b0 + jj;
      #pragma unroll
      for (int i2=0;i2<4;i2++){
        int rg = rt*64 + r0 + i2;
        if (rg<800) h2[b*800+rg] = fmaxf(acc[jj*4+i2] + b2[rg], 0.f);
      }
    }
  }
  post_done(h2d);
}

// mu_th / ls_th: 6 docs x 128 threads per block
static __device__ void muls_role(char* sm, int blk, const float* __restrict__ h2,
    const float* __restrict__ Wmu, const float* __restrict__ bmu,
    const float* __restrict__ Wls, const float* __restrict__ bls,
    float* __restrict__ muth, float* __restrict__ lsth, int* h2d, int* mulsd)
{
  pipe_wait<16>(h2d, 18);
  int sd = TID>>7, l = TID&127;
  int b = blk*6 + sd;
  bool bv = (b < 128);
  float* hS = (float*)sm + sd*800;
  if (bv){ for (int i=l;i<800;i+=128) hS[i] = h2[b*800+i]; }
  __syncthreads();
  if (bv){
    if (l<50){
      float a = bmu[l];
      const float* wp = Wmu + l*800;
      #pragma unroll 4
      for (int c=0;c<800;c++) a = fmaf(wp[c], hS[c], a);
      muth[b*50+l]=a;
    } else if (l>=64 && l<114){
      int r = l-64;
      float a = bls[r];
      const float* wp = Wls + r*800;
      #pragma unroll 4
      for (int c=0;c<800;c++) a = fmaf(wp[c], hS[c], a);
      lsth[b*50+r]=a;
    }
  }
  post_done(mulsd);
}

// theta + kl_theta: 12 docs (one wave each) per block
static __device__ void theta_role(int blk, const float* __restrict__ muth,
    const float* __restrict__ lsth, const float* __restrict__ etas,
    const int* __restrict__ times, const float* __restrict__ epsth,
    float* __restrict__ theta, float* acc, int* mulsd)
{
  pipe_wait<16>(mulsd, 22);
  int d = blk*12 + (TID>>6);
  int k = TID&63;
  if (d >= 128) return;
  bool a = k<50;
  int tb = times[d];
  float mu=0.f, ls=0.f, etd=0.f, z=-INFINITY;
  if (a){
    mu = muth[d*50+k]; ls = lsth[d*50+k]; etd = etas[tb*50+k];
    z = mu + epsth[d*50+k]*__expf(0.5f*ls);
  }
  float m=z;
  for (int o=32;o>0;o>>=1) m = fmaxf(m, __shfl_xor(m,o));
  float e = a ? __expf(z-m) : 0.f;
  float s = e;
  for (int o=32;o>0;o>>=1) s += __shfl_xor(s,o);
  if (a) theta[d*50+k] = e/s;
  float term = a ? ((__expf(ls)+(mu-etd)*(mu-etd))*(1.0f/(1.0f+1e-6f)) - 1.f - ls) : 0.f;
  for (int o=32;o>0;o>>=1) term += __shfl_xor(term,o);
  if (k==0) atomicAdd(acc+2, 0.5f*term);
}

__global__ __launch_bounds__(768,3) void k_mega(
    const float* __restrict__ pre0, const float* __restrict__ Whh,
    const float* __restrict__ Wih, const float* __restrict__ bih,
    const float* __restrict__ bhh, float* __restrict__ out0,
    float* __restrict__ out1, float* __restrict__ out2,
    float* __restrict__ pre1, float* __restrict__ pre2, int* __restrict__ flags,
    const float* __restrict__ Wmu_e, const float* __restrict__ bmu_e,
    const float* __restrict__ Wls_e, const float* __restrict__ bls_e,
    const float* __restrict__ eps_e, float* __restrict__ etas, float* acc,
    const float* __restrict__ rho, unsigned short* __restrict__ rho_f,
    const unsigned short* __restrict__ alpha_f,
    float* __restrict__ Mp, float* __restrict__ Sp,
    const float* __restrict__ nb, const float* __restrict__ W1,
    const float* __restrict__ b1, float* __restrict__ h1,
    const int* __restrict__ times, float* __restrict__ Mg, float* __restrict__ iSg,
    const float* __restrict__ W2, const float* __restrict__ b2, float* __restrict__ h2,
    const float* __restrict__ Wmu_t, const float* __restrict__ bmu_t,
    const float* __restrict__ Wls_t, const float* __restrict__ bls_t,
    float* __restrict__ muth, float* __restrict__ lsth,
    const float* __restrict__ eps_t, float* __restrict__ theta)
{
  __shared__ __align__(16) unsigned char smem[53248];
  char* sm = (char*)smem;
  int bid = blockIdx.x;
  if (bid==0)      lstm_rec (sm, pre0, Whh,        out0, nullptr,   flags+FG_S01);
  else if (bid==1) lstm_gemv(sm, out0, Wih+160000, bih+800,  bhh+800,  pre1, flags+FG_S01, flags+FG_S12);
  else if (bid==2) lstm_rec (sm, pre1, Whh+160000, out1, flags+FG_S12, flags+FG_S23);
  else if (bid==3) lstm_gemv(sm, out1, Wih+320000, bih+1600, bhh+1600, pre2, flags+FG_S23, flags+FG_S34);
  else if (bid==4) lstm_rec (sm, pre2, Whh+320000, out2, flags+FG_S34, flags+FG_S45);
  else if (bid==5) eta_stage(sm, out2, Wmu_e, bmu_e, Wls_e, bls_e, eps_e, etas, acc,
                             flags+FG_S45, flags+FG_ETAT);
  else if (bid<164){ int i=bid-6;   mf1_block(sm, i>>1, i&1, rho, rho_f, alpha_f, Mp, Sp, flags+FG_MF1D); }
  else if (bid<324){ int j=bid-164; h1_block(sm, j>>5, j&31, nb, W1, h1, flags+FG_H1D); }
  else if (bid<336){ msred_role(bid-324, Mp, Sp, Mg, iSg, flags+FG_MF1D); }
  else if (bid<352){ h1eta_role(sm, bid-336, etas, times, W1, b1, h1, flags+FG_ETAT, flags+FG_H1ED); }
  else if (bid<370){ h2_role(sm, bid-352, h1, W2, b2, h2, flags+FG_H1D, flags+FG_H1ED, flags+FG_H2D); }
  else if (bid<392){ muls_role(sm, bid-370, h2, Wmu_t, bmu_t, Wls_t, bls_t, muth, lsth,
                               flags+FG_H2D, flags+FG_MULSD); }
  else             { theta_role(bid-392, muth, lsth, etas, times, eps_t, theta, acc, flags+FG_MULSD); }
}

// ---------------- MFMA beta pass 2: recompute, normalize, fuse nll (+final) ------
__global__ __launch_bounds__(256,2) void k_mf2(const unsigned short* __restrict__ rho_f,
        const unsigned short* __restrict__ alpha_f,
        const float* __restrict__ Mg, const float* __restrict__ iSg,
        const float* __restrict__ theta, const int* __restrict__ times,
        const float* __restrict__ bows, float* acc,
        const int* __restrict__ nd, float* __restrict__ out, int* __restrict__ flags){
  __shared__ float thS[128*52];
  __shared__ float tileS[4][32*66];
  __shared__ int tS[128];
  __shared__ int cntS[64];
  int vb = blockIdx.x, tg = blockIdx.y;
  int wid = TID>>6, lane = TID&63;
  if (TID < 64) cntS[TID] = 0;
  __syncthreads();
  if (TID < 128){ int tv = times[TID]; tS[TID] = tv; atomicAdd(&cntS[tv], 1); }
  for (int i=TID; i<6400; i+=256){ int b=i/50, c=i%50; thS[b*52+c] = theta[i]; }
  int r32 = vb*4 + wid;
  const int4* ap = ((const int4*)rho_f) + (r32*19)*64 + lane;
  int4 a[19];
  #pragma unroll
  for (int ks=0;ks<19;ks++) a[ks] = ap[ks*64];
  __syncthreads();
  float local = 0.f;
  int rb32 = ((lane>>5)<<2);
  int c0 = lane&31, c1 = 32 + (lane&31);
  for (int t = tg*15; t < tg*15+15; t++){
    if (cntS[t] == 0) continue;
    v16f acc0, acc1;
    #pragma unroll
    for (int i=0;i<16;i++){ acc0[i]=0.f; acc1[i]=0.f; }
    const int4* bp = ((const int4*)alpha_f) + (t*38)*64 + lane;
    #pragma unroll
    for (int ks=0;ks<19;ks++){
      I4BF av, b0, b1;
      av.i = a[ks];
      b0.i = bp[ks*64];
      b1.i = bp[(19+ks)*64];
      acc0 = __builtin_amdgcn_mfma_f32_32x32x16_bf16(av.s, b0.s, acc0, 0,0,0);
      acc1 = __builtin_amdgcn_mfma_f32_32x32x16_bf16(av.s, b1.s, acc1, 0,0,0);
    }
    float M0 = Mg[t*50+c0], i0 = iSg[t*50+c0];
    float M1 = 0.f, i1 = 0.f;
    if (c1 < 50){ M1 = Mg[t*50+c1]; i1 = iSg[t*50+c1]; }
    float* tl = &tileS[wid][0];
    #pragma unroll
    for (int r=0;r<16;r++){
      int row = rb32 + (r&3) + ((r>>2)<<3);
      tl[row*66 + c0] = __expf(acc0[r]-M0)*i0;
      if (c1 < 50) tl[row*66 + c1] = __expf(acc1[r]-M1)*i1;
    }
    __syncthreads();
    for (int b=0;b<128;b++){
      if (tS[b] != t) continue;
      int row = lane&31;
      int v = vb*128 + wid*32 + row;
      const float* th = &thS[b*52 + (lane>>5)*25];
      const float* tp = &tl[row*66 + (lane>>5)*25];
      float mix = 0.f;
      #pragma unroll 5
      for (int c=0;c<25;c++) mix = fmaf(th[c], tp[c], mix);
      mix += __shfl_xor(mix, 32);
      if (lane < 32 && v < 30000)
        local -= __logf(mix + 1e-6f) * bows[b*30000 + v];
    }
    __syncthreads();
  }
  for (int o=1;o<64;o<<=1) local += __shfl_xor(local, o);
  if (lane==0) atomicAdd(acc+3, local);
  __syncthreads();
  if (TID==0){
    int n = __hip_atomic_fetch_add(flags+FG_MF2D, 1, __ATOMIC_ACQ_REL, __HIP_MEMORY_SCOPE_AGENT);
    if (n == 4*NVB-1){
      float coeff = (float)(*nd) / 128.0f;
      float nll = acc[3]*coeff;
      float klth = acc[2]*coeff;
      out[0] = nll + acc[0] + acc[1] + klth;
      out[1] = nll;
      out[2] = acc[0];
      out[3] = acc[1];
      out[4] = klth;
    }
  }
}

extern "C" void kernel_launch(void* const* d_in, const int* in_sizes, int n_in,
                              void* d_out, int out_size, void* d_ws, size_t ws_size,
                              hipStream_t stream) {
  (void)in_sizes; (void)n_in; (void)out_size; (void)ws_size;
  const float* bows  = (const float*)d_in[0];
  const float* nb    = (const float*)d_in[1];
  const int*   times = (const int*)d_in[2];
  const float* rnn   = (const float*)d_in[3];
  const int*   ndocs = (const int*)d_in[4];
  const float* eps_a = (const float*)d_in[5];
  const float* eps_e = (const float*)d_in[6];
  const float* eps_t = (const float*)d_in[7];
  const float* rho   = (const float*)d_in[8];
  const float* mqa   = (const float*)d_in[9];
  const float* lqa   = (const float*)d_in[10];
  const float* W1    = (const float*)d_in[11];
  const float* b1    = (const float*)d_in[12];
  const float* W2    = (const float*)d_in[13];
  const float* b2    = (const float*)d_in[14];
  const float* Wmu_t = (const float*)d_in[15];
  const float* bmu_t = (const float*)d_in[16];
  const float* Wls_t = (const float*)d_in[17];
  const float* bls_t = (const float*)d_in[18];
  const float* Wmap  = (const float*)d_in[19];
  const float* bmap  = (const float*)d_in[20];
  const float* Wih   = (const float*)d_in[21];
  const float* Whh   = (const float*)d_in[22];
  const float* bih   = (const float*)d_in[23];
  const float* bhh   = (const float*)d_in[24];
  const float* Wmu_e = (const float*)d_in[25];
  const float* bmu_e = (const float*)d_in[26];
  const float* Wls_e = (const float*)d_in[27];
  const float* bls_e = (const float*)d_in[28];
  float* out = (float*)d_out;

  float* p = (float*)d_ws;
  float* acc    = p; p += 8;
  unsigned short* rho_f   = (unsigned short*)p; p += 4572160;  // 940*19*64 int4
  unsigned short* alpha_f = (unsigned short*)p; p += 583680;   // 60*2*19*64 int4
  float* alphas = p; p += 900000;
  float* im     = p; p += 12000;
  float* out0   = p; p += 12000;
  float* out1   = p; p += 12000;
  float* out2   = p; p += 12000;
  float* pre0   = p; p += 48000;
  float* pre1   = p; p += 48000;
  float* pre2   = p; p += 48000;
  float* etas   = p; p += 3000;
  float* h1     = p; p += 102400;
  float* h2     = p; p += 102400;
  float* muth   = p; p += 6400;
  float* lsth   = p; p += 6400;
  float* theta  = p; p += 6400;
  float* Mp     = p; p += 3000*NVB2;
  float* Sp     = p; p += 3000*NVB2;
  float* Mg     = p; p += 3000;
  float* iSg    = p; p += 3000;
  int*   flags  = (int*)p; p += 256;

  k_zero<<<1,256,0,stream>>>(acc, flags);
  (void)hipMemsetAsync(h1, 0, 102400*sizeof(float), stream);
  k_alphakl<<<3516,256,0,stream>>>(mqa, lqa, eps_a, alphas, acc);
  k_prep_alpha<<<570,256,0,stream>>>(alphas, alpha_f);
  k_iminit<<<47,256,0,stream>>>(im, bmap);
  k_imgemm<<<dim3(7,60),256,0,stream>>>(rnn, Wmap, im);
  k_pregates<<<dim3(60,4),256,0,stream>>>(im, Wih, bih, bhh, pre0);

  // mega: 6 pipe + 158 mf1 + 160 h1 + 12 msred + 16 h1eta + 18 h2 + 22 muls + 11 theta = 403
  k_mega<<<403,768,0,stream>>>(pre0, Whh, Wih, bih, bhh, out0, out1, out2,
                               pre1, pre2, flags,
                               Wmu_e, bmu_e, Wls_e, bls_e, eps_e, etas, acc,
                               rho, rho_f, alpha_f, Mp, Sp,
                               nb, W1, b1, h1, times, Mg, iSg,
                               W2, b2, h2, Wmu_t, bmu_t, Wls_t, bls_t,
                               muth, lsth, eps_t, theta);

  k_mf2<<<dim3(NVB,4),256,0,stream>>>(rho_f, alpha_f, Mg, iSg, theta, times, bows, acc,
                                      ndocs, out, flags);
}

// Round 5
// 1502.118 us; speedup vs baseline: 1.1235x; 1.1235x over previous
//
#include <hip/hip_runtime.h>
#include <hip/hip_fp16.h>
#include <math.h>

#define TID ((int)threadIdx.x)

// dims: V=30000 K=50 E=300 T=60 B=128 TH=800 H=200 L=3
// mega-mf1: NVB2=79 v-blocks of 384 rows x 4 tg; mf2n: 79 vb x 2 tg, 768 thr
#define NVB2 79

// flag indices
#define FG_S01   0
#define FG_S12   32
#define FG_S23   64
#define FG_S34   96
#define FG_S45   128
#define FG_ETAT  160
#define FG_MF1D  192
#define FG_MF2D  212

static __device__ __forceinline__ float sigf(float x){ return 1.f/(1.f+__expf(-x)); }
static __device__ __forceinline__ float tanhfast(float x){
  float t = fminf(fmaxf(x,-15.f),15.f);
  float e = __expf(2.f*t);
  return (e-1.f)/(e+1.f);
}

static __device__ __forceinline__ unsigned short f2bf(float f){
  unsigned u = __float_as_uint(f);
  unsigned r = (u + 0x7FFFu + ((u>>16)&1u)) >> 16;
  return (unsigned short)r;
}

typedef short v8ss __attribute__((ext_vector_type(8)));
typedef float v16f __attribute__((ext_vector_type(16)));
union I4BF { int4 i; v8ss s; };
union U16B { int4 i; __half2 h2[4]; };

#define REP25(M) M(0) M(1) M(2) M(3) M(4) M(5) M(6) M(7) M(8) M(9) M(10) M(11) \
                 M(12) M(13) M(14) M(15) M(16) M(17) M(18) M(19) M(20) M(21) M(22) M(23) M(24)

#define DECLWF(n) int4 w##n; { float4 fA = rowF[2*(n)], fB = rowF[2*(n)+1]; U16B u; \
    u.h2[0]=__floats2half2_rn(fA.x,fA.y); u.h2[1]=__floats2half2_rn(fA.z,fA.w); \
    u.h2[2]=__floats2half2_rn(fB.x,fB.y); u.h2[3]=__floats2half2_rn(fB.z,fB.w); w##n=u.i; }

#define DOTW(n) { U16B u; u.i = w##n; \
    float4 hA = hs4[2*(n)], hB = hs4[2*(n)+1]; \
    float2 q0=__half22float2(u.h2[0]), q1=__half22float2(u.h2[1]); \
    float2 q2=__half22float2(u.h2[2]), q3=__half22float2(u.h2[3]); \
    a0=fmaf(q0.x,hA.x,a0); a1=fmaf(q0.y,hA.y,a1); \
    a2=fmaf(q1.x,hA.z,a2); a3=fmaf(q1.y,hA.w,a3); \
    a0=fmaf(q2.x,hB.x,a0); a1=fmaf(q2.y,hB.y,a1); \
    a2=fmaf(q3.x,hB.z,a2); a3=fmaf(q3.y,hB.w,a3); }

// ---------------- init ----------------
__global__ void k_zero(float* acc, int* flags){
  if (TID<8) acc[TID]=0.f;
  if (TID<256) flags[TID]=0;
}

// ---------------- alphas + kl_alpha (merged; recompute prev alpha) ----------------
__global__ void k_alphakl(const float* __restrict__ mqa, const float* __restrict__ lqa,
                          const float* __restrict__ eps, float* __restrict__ alphas,
                          float* acc){
  __shared__ float red[256];
  int i = blockIdx.x*256+TID;
  float term = 0.f;
  if (i<900000){
    int t = i/15000, r = i%15000, k = r/300, e = r%300;
    int src = k*18000 + t*300 + e;
    float mu = mqa[src], ls = lqa[src];
    alphas[i] = mu + eps[i]*__expf(0.5f*ls);
    if (t==0){
      term = (__expf(ls)+mu*mu)*(1.0f/(1.0f+1e-6f)) - 1.f - ls;
    } else {
      int sp = src - 300;
      float mup = mqa[sp], lsp = lqa[sp];
      float ap = mup + eps[i-15000]*__expf(0.5f*lsp);
      float d = mu - ap;
      term = (__expf(ls)+d*d)*(1.0f/(0.005f+1e-6f)) - 1.f + logf(0.005f) - ls;
    }
  }
  red[TID]=term; __syncthreads();
  for (int s=128;s>0;s>>=1){ if (TID<s) red[TID]+=red[TID+s]; __syncthreads(); }
  if (TID==0) atomicAdd(acc+0, 0.5f*red[0]);
}

// ---------------- bf16 fragment prep ----------------
__global__ void k_prep_rho(const float* __restrict__ rho, unsigned short* __restrict__ rho_f){
  int tid = blockIdx.x*256+TID;
  if (tid >= 940*19*64) return;
  int lane = tid & 63;
  int F = tid >> 6;
  int kstep = F % 19;
  int r32 = F / 19;
  int v = r32*32 + (lane & 31);
  int e0 = kstep*16 + ((lane>>5)<<3);
  unsigned short u[8];
  #pragma unroll
  for (int j=0;j<8;j++){
    int e = e0 + j;
    float val = (v < 30000 && e < 300) ? rho[v*300 + e] : 0.f;
    u[j] = f2bf(val);
  }
  int4 o;
  o.x = (int)u[0] | ((int)u[1]<<16);
  o.y = (int)u[2] | ((int)u[3]<<16);
  o.z = (int)u[4] | ((int)u[5]<<16);
  o.w = (int)u[6] | ((int)u[7]<<16);
  ((int4*)rho_f)[tid] = o;
}

__global__ void k_prep_alpha(const float* __restrict__ alphas, unsigned short* __restrict__ alpha_f){
  int tid = blockIdx.x*256+TID;
  if (tid >= 60*2*19*64) return;
  int lane = tid & 63;
  int F = tid >> 6;
  int kstep = F % 19;
  int tn = F / 19;
  int nt = tn % 2, t = tn / 2;
  int k = nt*32 + (lane & 31);
  int e0 = kstep*16 + ((lane>>5)<<3);
  unsigned short u[8];
  #pragma unroll
  for (int j=0;j<8;j++){
    int e = e0 + j;
    float val = (k < 50 && e < 300) ? alphas[t*15000 + k*300 + e] : 0.f;
    u[j] = f2bf(val);
  }
  int4 o;
  o.x = (int)u[0] | ((int)u[1]<<16);
  o.y = (int)u[2] | ((int)u[3]<<16);
  o.z = (int)u[4] | ((int)u[5]<<16);
  o.w = (int)u[6] | ((int)u[7]<<16);
  ((int4*)alpha_f)[tid] = o;
}

// ---------------- inp_map = rnn_inp @ Wmap.T + bmap ----------------
__global__ void k_iminit(float* __restrict__ im, const float* __restrict__ bmap){
  int i = blockIdx.x*256+TID; if (i<12000) im[i] = bmap[i%200];
}

__global__ __launch_bounds__(256,2) void k_imgemm(const float* __restrict__ rnn,
        const float* __restrict__ Wmap, float* __restrict__ im){
  __shared__ __align__(16) float Ws[32*500];
  __shared__ __align__(16) float rnS[500];
  int hb = blockIdx.x;       // 0..6
  int kb = blockIdx.y;       // 0..59
  int h0 = hb*32;
  int nh = (h0+32<=200)?32:(200-h0);
  const int kbase = kb*500;
  for (int i=TID; i<nh*125; i+=256){
    int h = i/125, q = i%125;
    *reinterpret_cast<float4*>(&Ws[h*500 + q*4]) =
      *reinterpret_cast<const float4*>(&Wmap[(h0+h)*30000 + kbase + q*4]);
  }
  int h = TID>>3, sub = TID&7;
  bool act = (h < nh);
  __syncthreads();
  for (int t=0;t<60;t++){
    if (TID<125)
      *reinterpret_cast<float4*>(&rnS[TID*4]) =
        *reinterpret_cast<const float4*>(&rnn[t*30000 + kbase + TID*4]);
    __syncthreads();
    float a = 0.f;
    if (act){
      const float2* wp = reinterpret_cast<const float2*>(&Ws[h*500]);
      const float2* rp = reinterpret_cast<const float2*>(rnS);
      for (int k2=sub;k2<250;k2+=8){
        float2 wv=wp[k2], rv=rp[k2];
        a = fmaf(wv.x,rv.x,a); a = fmaf(wv.y,rv.y,a);
      }
    }
    a += __shfl_down(a,4); a += __shfl_down(a,2); a += __shfl_down(a,1);
    if (act && sub==0) atomicAdd(&im[t*200 + h0 + h], a);
    __syncthreads();
  }
}

// ---------------- LSTM pre-gates (layer 0 only) ----------------
__global__ void k_pregates(const float* __restrict__ x, const float* __restrict__ Wih,
                           const float* __restrict__ bih, const float* __restrict__ bhh,
                           float* __restrict__ pre){
  __shared__ float xS[200];
  int t = blockIdx.x;
  if (TID<200) xS[TID] = x[t*200+TID];
  __syncthreads();
  int r = blockIdx.y*256 + TID;
  if (r>=800) return;
  float a = bih[r] + bhh[r];
  const float* wp = Wih + r*200;
  #pragma unroll 4
  for (int c=0;c<200;c++) a = fmaf(wp[c], xS[c], a);
  pre[t*800+r] = a;
}

// ================= MEGA KERNEL =================
// blocks 0-5: LSTM pipe (rec0,gemv1,rec1,gemv2,rec2,eta)
// 6-21: h1eta (16 x 8 docs, per-doc eta overlap)   22-33: msred
// 34-349: mf1 (79 vb x 4 tg)                      350-509: h1 main GEMM
// 510 blocks <= 512 resident slots (2/CU at 53KB LDS) => spin-waits deadlock-free.

template<int SLP>
static __device__ __forceinline__ void pipe_wait(int* flag, int val){
  if (TID==0){
    while (__hip_atomic_load(flag, __ATOMIC_RELAXED, __HIP_MEMORY_SCOPE_AGENT) < val)
      __builtin_amdgcn_s_sleep(SLP);
    (void)__hip_atomic_load(flag, __ATOMIC_ACQUIRE, __HIP_MEMORY_SCOPE_AGENT);
  }
  __syncthreads();
}

static __device__ __forceinline__ void pipe_post(int* flag, int val){
  if (TID==0)
    __hip_atomic_store(flag, val, __ATOMIC_RELEASE, __HIP_MEMORY_SCOPE_AGENT);
}

static __device__ __forceinline__ void post_done(int* ctr){
  __syncthreads();
  if (TID==0)
    __hip_atomic_fetch_add(ctr, 1, __ATOMIC_RELEASE, __HIP_MEMORY_SCOPE_AGENT);
}

// recurrent cell chain: weights f32->f16 inline into 25 named int4 regs
static __device__ void lstm_rec(char* sm, const float* __restrict__ pre,
    const float* __restrict__ WhhF, float* __restrict__ out,
    int* inFlag, int* outFlag)
{
  float* hsF = (float*)sm;              // 200 f
  float* gsh = (float*)(sm + 800);      // 800 f
  __half* wtH = (__half*)(sm + 4000);   // 6400 h
  for (int i=TID;i<6400;i+=768) wtH[i] = __float2half_rn(WhhF[768*200 + i]);
  const float4* rowF = reinterpret_cast<const float4*>(WhhF + TID*200);
  REP25(DECLWF)
  float c_reg = 0.f;
  if (TID<200) hsF[TID]=0.f;
  int j = TID - 512;
  int trow = (j>=0) ? (j>>3) : 0;
  int tseg = (j>=0) ? (j&7)*25 : 0;
  __syncthreads();
  for (int t=0;t<60;t++){
    if (inFlag) pipe_wait<1>(inFlag, t+1);
    float p = pre[t*800+TID];
    float a0=0.f,a1=0.f,a2=0.f,a3=0.f;
    const float4* hs4 = reinterpret_cast<const float4*>(hsF);
    REP25(DOTW)
    gsh[TID] = a0+a1+a2+a3 + p;
    if (j>=0){
      float pa = 0.f;
      const __half* wt = &wtH[trow*200 + tseg];
      const float* hp = &hsF[tseg];
      #pragma unroll
      for (int c2=0;c2<25;c2++) pa = fmaf(__half2float(wt[c2]), hp[c2], pa);
      pa += __shfl_down(pa,4); pa += __shfl_down(pa,2); pa += __shfl_down(pa,1);
      if ((j&7)==0) gsh[768+trow] = pa + pre[t*800+768+trow];
    }
    __syncthreads();
    if (TID<200){
      float ii=gsh[TID], ff=gsh[200+TID], gg=gsh[400+TID], oo=gsh[600+TID];
      float c = sigf(ff)*c_reg + sigf(ii)*tanhfast(gg);
      c_reg = c;
      float h = sigf(oo)*tanhfast(c);
      hsF[TID]=h;
      out[t*200+TID]=h;
    }
    __syncthreads();
    if (outFlag) pipe_post(outFlag, t+1);
  }
}

// input-gemv stage: pre_l[t] = Wih_l @ out_{l-1}[t] + bih + bhh
static __device__ void lstm_gemv(char* sm, const float* __restrict__ xIn,
    const float* __restrict__ WF, const float* __restrict__ bih,
    const float* __restrict__ bhh, float* __restrict__ preOut,
    int* inFlag, int* outFlag)
{
  float* xS = (float*)sm;               // 200 f
  __half* wtG = (__half*)(sm + 800);    // 6400 h
  for (int i=TID;i<6400;i+=768) wtG[i] = __float2half_rn(WF[768*200 + i]);
  const float4* rowF = reinterpret_cast<const float4*>(WF + TID*200);
  REP25(DECLWF)
  float bb = bih[TID] + bhh[TID];
  int j = TID - 512;
  int trow = (j>=0) ? (j>>3) : 0;
  int tseg = (j>=0) ? (j&7)*25 : 0;
  float bbT = 0.f;
  if (j>=0 && (j&7)==0) bbT = bih[768+trow] + bhh[768+trow];
  for (int t=0;t<60;t++){
    pipe_wait<1>(inFlag, t+1);
    if (TID<200) xS[TID] = xIn[t*200+TID];
    __syncthreads();
    float a0=0.f,a1=0.f,a2=0.f,a3=0.f;
    const float4* hs4 = reinterpret_cast<const float4*>(xS);
    REP25(DOTW)
    preOut[t*800+TID] = a0+a1+a2+a3 + bb;
    if (j>=0){
      float pa = 0.f;
      const __half* wt = &wtG[trow*200 + tseg];
      const float* hp = &xS[tseg];
      #pragma unroll
      for (int c2=0;c2<25;c2++) pa = fmaf(__half2float(wt[c2]), hp[c2], pa);
      pa += __shfl_down(pa,4); pa += __shfl_down(pa,2); pa += __shfl_down(pa,1);
      if ((j&7)==0) preOut[t*800+768+trow] = pa + bbT;
    }
    __syncthreads();
    pipe_post(outFlag, t+1);
  }
}

// eta chain as 6th pipeline stage; posts per-t flag for h1eta consumers
static __device__ void eta_stage(char* sm, const float* __restrict__ outF,
    const float* __restrict__ Wmu, const float* __restrict__ bmu,
    const float* __restrict__ Wls, const float* __restrict__ bls,
    const float* __restrict__ eps, float* __restrict__ etas, float* acc,
    int* inFlag, int* etaT)
{
  __half* wS = (__half*)sm;                 // 100*254 h = 50800 B
  float* inp = (float*)(sm + 50816);        // 256 f
  float* pt  = (float*)(sm + 51840);        // 200 f
  float* muS = (float*)(sm + 52640);        // 64 f
  float* lsS = (float*)(sm + 52896);        // 64 f
  for (int i=TID;i<12500;i+=768) wS[(i/250)*254 + (i%250)] = __float2half_rn(Wmu[i]);
  for (int i=TID;i<12500;i+=768) wS[(50+i/250)*254 + (i%250)] = __float2half_rn(Wls[i]);
  if (TID<50) inp[200+TID]=0.f;
  const float LOGD = logf(0.005f);
  float kacc = 0.f;
  __syncthreads();
  for (int t=0;t<60;t++){
    pipe_wait<1>(inFlag, t+1);
    if (TID<200) inp[TID] = outF[t*200+TID];
    __syncthreads();
    if (TID<200){
      int rr = TID%100, hf = TID/100;
      const __half* wp = &wS[rr*254 + hf*125];
      const float* ip = &inp[hf*125];
      float s=0.f;
      for (int c=0;c<125;c++) s = fmaf(__half2float(wp[c]), ip[c], s);
      pt[TID]=s;
    }
    __syncthreads();
    if (TID<100){
      float v = pt[TID]+pt[TID+100];
      if (TID<50) muS[TID] = v + bmu[TID];
      else lsS[TID-50] = v + bls[TID-50];
    }
    __syncthreads();
    if (TID<64){
      float term=0.f;
      if (TID<50){
        float mu=muS[TID], ls=lsS[TID], ep=inp[200+TID];
        if (t==0) term = (__expf(ls)+mu*mu)*(1.0f/(1.0f+1e-6f)) - 1.f - ls;
        else { float d=mu-ep; term = (__expf(ls)+d*d)*(1.0f/(0.005f+1e-6f)) - 1.f + LOGD - ls; }
        float et = mu + eps[t*50+TID]*__expf(0.5f*ls);
        etas[t*50+TID]=et;
        inp[200+TID]=et;
      }
      for (int o=32;o>0;o>>=1) term += __shfl_down(term,o);
      if (TID==0) kacc += 0.5f*term;
    }
    __syncthreads();
    pipe_post(etaT, t+1);
  }
  if (TID==0) atomicAdd(acc+1, kacc);
}

// MFMA beta pass 1: 12 waves = 384 v-rows per block, 15 t per block
static __device__ void mf1_block(char* sm, int vb, int tg,
    const unsigned short* __restrict__ rho_f, const unsigned short* __restrict__ alpha_f,
    float* __restrict__ Mp, float* __restrict__ Sp, int* mf1d)
{
  float* redM = (float*)sm;            // 12*64 f
  float* redS = (float*)(sm + 3072);   // 12*64 f
  int wid = TID>>6, lane = TID&63;
  int r32 = vb*12 + wid;
  bool valid = (r32 < 940);
  int4 zi; zi.x=0; zi.y=0; zi.z=0; zi.w=0;
  const int4* ap = ((const int4*)rho_f) + (r32*19)*64 + lane;
  int4 a[19];
  #pragma unroll
  for (int ks=0;ks<19;ks++) a[ks] = valid ? ap[ks*64] : zi;
  int rowbase = vb*384 + wid*32 + ((lane>>5)<<2);
  for (int t = tg*15; t < tg*15+15; t++){
    v16f acc0, acc1;
    #pragma unroll
    for (int i=0;i<16;i++){ acc0[i]=0.f; acc1[i]=0.f; }
    const int4* bp = ((const int4*)alpha_f) + (t*38)*64 + lane;
    #pragma unroll
    for (int ks=0;ks<19;ks++){
      I4BF av, b0, b1;
      av.i = a[ks];
      b0.i = bp[ks*64];
      b1.i = bp[(19+ks)*64];
      acc0 = __builtin_amdgcn_mfma_f32_32x32x16_bf16(av.s, b0.s, acc0, 0,0,0);
      acc1 = __builtin_amdgcn_mfma_f32_32x32x16_bf16(av.s, b1.s, acc1, 0,0,0);
    }
    float m0=-INFINITY, m1=-INFINITY;
    #pragma unroll
    for (int r=0;r<16;r++){
      int v = rowbase + (r&3) + ((r>>2)<<3);
      if (v < 30000){ m0 = fmaxf(m0, acc0[r]); m1 = fmaxf(m1, acc1[r]); }
    }
    m0 = fmaxf(m0, __shfl_xor(m0, 32));
    m1 = fmaxf(m1, __shfl_xor(m1, 32));
    float s0=0.f, s1=0.f;
    #pragma unroll
    for (int r=0;r<16;r++){
      int v = rowbase + (r&3) + ((r>>2)<<3);
      if (v < 30000){ s0 += __expf(acc0[r]-m0); s1 += __expf(acc1[r]-m1); }
    }
    s0 += __shfl_xor(s0, 32);
    s1 += __shfl_xor(s1, 32);
    if (lane < 32){
      redM[wid*64+lane] = m0; redM[wid*64+lane+32] = m1;
      redS[wid*64+lane] = s0; redS[wid*64+lane+32] = s1;
    }
    __syncthreads();
    if (TID < 50){
      float M = redM[TID];
      #pragma unroll
      for (int w2=1; w2<12; w2++) M = fmaxf(M, redM[w2*64+TID]);
      float S = 0.f;
      #pragma unroll
      for (int w2=0; w2<12; w2++){
        float mw = redM[w2*64+TID];
        if (mw > -INFINITY) S += redS[w2*64+TID] * __expf(mw - M);
      }
      Mp[(t*50+TID)*NVB2 + vb] = M;
      Sp[(t*50+TID)*NVB2 + vb] = S;
    }
    __syncthreads();
  }
  post_done(mf1d);
}

// h1 main GEMM (k<30000 only): 3 rt-tiles share one A-tile
static __device__ void h1_block(char* sm, int rtg, int sp,
    const float* __restrict__ nb, const float* __restrict__ W1,
    float* __restrict__ h1)
{
  float* As = (float*)sm;               // 16*132 f
  float* WsAll = (float*)(sm + 8448);   // 3 * 16*68 f
  int sub = TID>>8, l = TID&255;
  int rt = rtg*3 + sub;                 // 0..14 (rows >=800 masked)
  float* Ws = WsAll + sub*(16*68);
  int kbeg = sp*940;
  int kend = kbeg+940; if (kend>30000) kend=30000;
  int b0 = (l%32)*4, r0 = (l/32)*8;
  float acc[32];
  #pragma unroll
  for (int jj=0;jj<32;jj++) acc[jj]=0.f;
  for (int kb=kbeg; kb<kend; kb+=16){
    __syncthreads();
    for (int i=TID;i<2048;i+=768){
      int b=i>>4, kk=i&15, kg=kb+kk;
      As[kk*132+b] = (kg<kend) ? nb[b*30000+kg] : 0.f;
    }
    for (int i=l;i<1024;i+=256){
      int r=i>>4, kk=i&15, kg=kb+kk, rg=rt*64+r;
      Ws[kk*68+r] = (kg<kend && rg<800) ? W1[rg*30050+kg] : 0.f;
    }
    __syncthreads();
    #pragma unroll
    for (int kk=0;kk<16;kk++){
      float4 a4 = *reinterpret_cast<const float4*>(&As[kk*132+b0]);
      float4 w4 = *reinterpret_cast<const float4*>(&Ws[kk*68+r0]);
      float4 w5 = *reinterpret_cast<const float4*>(&Ws[kk*68+r0+4]);
      float aa[4]={a4.x,a4.y,a4.z,a4.w};
      float ww[8]={w4.x,w4.y,w4.z,w4.w,w5.x,w5.y,w5.z,w5.w};
      #pragma unroll
      for (int j=0;j<4;j++)
        #pragma unroll
        for (int i2=0;i2<8;i2++) acc[j*8+i2] = fmaf(aa[j], ww[i2], acc[j*8+i2]);
    }
  }
  #pragma unroll
  for (int j=0;j<4;j++){
    int b=b0+j;
    #pragma unroll
    for (int i2=0;i2<8;i2++){
      int rg = rt*64+r0+i2;
      if (rg<800) atomicAdd(&h1[b*800+rg], acc[j*8+i2]);
    }
  }
}

// reduce Mp/Sp partials -> Mg, 1/S (12 blocks x 12 waves)
static __device__ void msred_role(int blk, const float* __restrict__ Mp,
    const float* __restrict__ Sp, float* __restrict__ Mg, float* __restrict__ iSg,
    int* mf1d)
{
  pipe_wait<16>(mf1d, 316);
  int w = TID>>6, lane = TID&63;
  for (int row = blk*12 + w; row < 3000; row += 144){
    float m0 = (lane < NVB2) ? Mp[row*NVB2 + lane] : -INFINITY;
    float m1 = (64+lane < NVB2) ? Mp[row*NVB2 + 64 + lane] : -INFINITY;
    float s0 = (lane < NVB2) ? Sp[row*NVB2 + lane] : 0.f;
    float s1 = (64+lane < NVB2) ? Sp[row*NVB2 + 64 + lane] : 0.f;
    float mm = fmaxf(m0, m1);
    for (int o=32;o>0;o>>=1) mm = fmaxf(mm, __shfl_xor(mm,o));
    float e = 0.f;
    if (m0 > -INFINITY) e += s0*__expf(m0-mm);
    if (m1 > -INFINITY) e += s1*__expf(m1-mm);
    for (int o=32;o>0;o>>=1) e += __shfl_xor(e,o);
    if (lane==0){ Mg[row]=mm; iSg[row]=1.f/e; }
  }
}

// eta columns of h1 + bias (per-doc overlap with eta pipeline)
static __device__ void h1eta_role(char* sm, int blk, const float* __restrict__ etas,
    const int* __restrict__ times, const float* __restrict__ W1,
    const float* __restrict__ b1, float* __restrict__ h1, int* etaT)
{
  float* eS = (float*)sm;  // 64 f
  for (int d=0; d<8; d++){
    int b = blk*8 + d;
    int tb = times[b];
    pipe_wait<4>(etaT, tb+1);
    if (TID<50) eS[TID] = etas[tb*50+TID];
    __syncthreads();
    for (int r=TID; r<800; r+=768){
      const float* wp = W1 + r*30050 + 30000;
      float a2 = b1[r];
      #pragma unroll 10
      for (int c=0;c<50;c++) a2 = fmaf(wp[c], eS[c], a2);
      atomicAdd(&h1[b*800+r], a2);
    }
    __syncthreads();
  }
}

__global__ __launch_bounds__(768,3) void k_mega(
    const float* __restrict__ pre0, const float* __restrict__ Whh,
    const float* __restrict__ Wih, const float* __restrict__ bih,
    const float* __restrict__ bhh, float* __restrict__ out0,
    float* __restrict__ out1, float* __restrict__ out2,
    float* __restrict__ pre1, float* __restrict__ pre2, int* __restrict__ flags,
    const float* __restrict__ Wmu_e, const float* __restrict__ bmu_e,
    const float* __restrict__ Wls_e, const float* __restrict__ bls_e,
    const float* __restrict__ eps_e, float* __restrict__ etas, float* acc,
    const unsigned short* __restrict__ rho_f, const unsigned short* __restrict__ alpha_f,
    float* __restrict__ Mp, float* __restrict__ Sp,
    const float* __restrict__ nb, const float* __restrict__ W1,
    const float* __restrict__ b1, float* __restrict__ h1,
    const int* __restrict__ times, float* __restrict__ Mg, float* __restrict__ iSg)
{
  __shared__ __align__(16) unsigned char smem[53248];
  char* sm = (char*)smem;
  int bid = blockIdx.x;
  if (bid==0)      lstm_rec (sm, pre0, Whh,        out0, nullptr,   flags+FG_S01);
  else if (bid==1) lstm_gemv(sm, out0, Wih+160000, bih+800,  bhh+800,  pre1, flags+FG_S01, flags+FG_S12);
  else if (bid==2) lstm_rec (sm, pre1, Whh+160000, out1, flags+FG_S12, flags+FG_S23);
  else if (bid==3) lstm_gemv(sm, out1, Wih+320000, bih+1600, bhh+1600, pre2, flags+FG_S23, flags+FG_S34);
  else if (bid==4) lstm_rec (sm, pre2, Whh+320000, out2, flags+FG_S34, flags+FG_S45);
  else if (bid==5) eta_stage(sm, out2, Wmu_e, bmu_e, Wls_e, bls_e, eps_e, etas, acc,
                             flags+FG_S45, flags+FG_ETAT);
  else if (bid<22){ h1eta_role(sm, bid-6, etas, times, W1, b1, h1, flags+FG_ETAT); }
  else if (bid<34){ msred_role(bid-22, Mp, Sp, Mg, iSg, flags+FG_MF1D); }
  else if (bid<350){ int i=bid-34;  mf1_block(sm, i>>2, i&3, rho_f, alpha_f, Mp, Sp, flags+FG_MF1D); }
  else             { int j=bid-350; h1_block(sm, j>>5, j&31, nb, W1, h1); }
}

// ---------------- h2 = relu(relu(h1) @ W2.T + b2), tiled 32x64 ----------------
__global__ __launch_bounds__(256) void k_h2(const float* __restrict__ h1,
        const float* __restrict__ W2, const float* __restrict__ b2,
        float* __restrict__ h2){
  __shared__ __align__(16) float As[16*33];
  __shared__ __align__(16) float Ws[16*68];
  int bt = blockIdx.x;  // 0..3
  int rt = blockIdx.y;  // 0..12
  int b0 = (TID%16)*2, r0 = (TID/16)*4;
  float acc[8] = {0,0,0,0,0,0,0,0};
  for (int kb=0; kb<800; kb+=16){
    __syncthreads();
    for (int i=TID;i<512;i+=256){
      int b=i>>4, k=i&15;
      As[k*33+b] = fmaxf(h1[(bt*32+b)*800 + kb + k], 0.f);
    }
    for (int i=TID;i<1024;i+=256){
      int r=i>>4, k=i&15; int rg = rt*64+r;
      Ws[k*68+r] = (rg<800) ? W2[rg*800 + kb + k] : 0.f;
    }
    __syncthreads();
    #pragma unroll
    for (int k=0;k<16;k++){
      float a0=As[k*33+b0], a1=As[k*33+b0+1];
      float4 w4 = *reinterpret_cast<const float4*>(&Ws[k*68+r0]);
      acc[0]=fmaf(a0,w4.x,acc[0]); acc[1]=fmaf(a0,w4.y,acc[1]);
      acc[2]=fmaf(a0,w4.z,acc[2]); acc[3]=fmaf(a0,w4.w,acc[3]);
      acc[4]=fmaf(a1,w4.x,acc[4]); acc[5]=fmaf(a1,w4.y,acc[5]);
      acc[6]=fmaf(a1,w4.z,acc[6]); acc[7]=fmaf(a1,w4.w,acc[7]);
    }
  }
  #pragma unroll
  for (int jj=0;jj<2;jj++){
    int b = bt*32 + b0 + jj;
    #pragma unroll
    for (int i2=0;i2<4;i2++){
      int rg = rt*64 + r0 + i2;
      if (rg<800) h2[b*800+rg] = fmaxf(acc[jj*4+i2] + b2[rg], 0.f);
    }
  }
}

// ---------------- mu_th / ls_th ----------------
__global__ void k_muls(const float* __restrict__ h2, const float* __restrict__ Wmu,
                       const float* __restrict__ bmu, const float* __restrict__ Wls,
                       const float* __restrict__ bls, float* __restrict__ muth,
                       float* __restrict__ lsth){
  __shared__ float hS[800];
  int b = blockIdx.x;
  for (int i=TID;i<800;i+=128) hS[i] = h2[b*800+i];
  __syncthreads();
  if (TID<50){
    float a = bmu[TID];
    const float* wp = Wmu + TID*800;
    #pragma unroll 4
    for (int c=0;c<800;c++) a = fmaf(wp[c], hS[c], a);
    muth[b*50+TID]=a;
  } else if (TID>=64 && TID<114){
    int r = TID-64;
    float a = bls[r];
    const float* wp = Wls + r*800;
    #pragma unroll 4
    for (int c=0;c<800;c++) a = fmaf(wp[c], hS[c], a);
    lsth[b*50+r]=a;
  }
}

// ---------------- theta + kl_theta ----------------
__global__ void k_theta(const float* __restrict__ muth, const float* __restrict__ lsth,
                        const float* __restrict__ etas, const int* __restrict__ times,
                        const float* __restrict__ epsth, float* __restrict__ theta,
                        float* acc){
  int b = blockIdx.x, k = TID;
  bool a = k<50;
  int tb = times[b];
  float mu=0.f, ls=0.f, etd=0.f, z=-INFINITY;
  if (a){
    mu = muth[b*50+k]; ls = lsth[b*50+k]; etd = etas[tb*50+k];
    z = mu + epsth[b*50+k]*__expf(0.5f*ls);
  }
  float m=z;
  for (int o=32;o>0;o>>=1) m = fmaxf(m, __shfl_xor(m,o));
  float e = a ? __expf(z-m) : 0.f;
  float s = e;
  for (int o=32;o>0;o>>=1) s += __shfl_xor(s,o);
  if (a) theta[b*50+k] = e/s;
  float term = a ? ((__expf(ls)+(mu-etd)*(mu-etd))*(1.0f/(1.0f+1e-6f)) - 1.f - ls) : 0.f;
  for (int o=32;o>0;o>>=1) term += __shfl_xor(term,o);
  if (TID==0) atomicAdd(acc+2, 0.5f*term);
}

// ---------------- MFMA beta pass 2, transposed: D[k][v], v = lane&31 ----------------
// mfma(alpha_frag, rho_frag) -> row=k (regs), col=v (lanes). Doc dot is in-register
// over lane-local k, one shfl_xor(32) to combine k-halves, coalesced bows loads.
__global__ __launch_bounds__(768) void k_mf2n(const unsigned short* __restrict__ rho_f,
        const unsigned short* __restrict__ alpha_f,
        const float* __restrict__ Mg, const float* __restrict__ iSg,
        const float* __restrict__ theta, const int* __restrict__ times,
        const float* __restrict__ bows, float* acc,
        const int* __restrict__ nd, float* __restrict__ out, int* __restrict__ flags){
  __shared__ float thS[128*52];
  __shared__ int tSd[128];
  __shared__ int dlist[128];
  __shared__ int dstart[61];
  __shared__ float redL[12];
  int vb = blockIdx.x >> 1;      // 0..78
  int tg = blockIdx.x & 1;       // 0..1
  int wid = TID>>6, lane = TID&63;
  int h = lane>>5;
  for (int i=TID; i<6400; i+=768){ int b=i/50, c=i%50; thS[b*52+c] = theta[i]; }
  if (TID<128) tSd[TID] = times[TID];
  __syncthreads();
  if (TID==0){
    int cnt[60];
    #pragma unroll
    for (int t=0;t<60;t++) cnt[t]=0;
    for (int b=0;b<128;b++) cnt[tSd[b]]++;
    int o=0;
    for (int t=0;t<60;t++){ dstart[t]=o; o+=cnt[t]; cnt[t]=dstart[t]; }
    dstart[60]=o;
    for (int b=0;b<128;b++){ int t=tSd[b]; dlist[cnt[t]++]=b; }
  }
  __syncthreads();
  // rho fragments (B operand): wave's 32-v block
  int r32 = vb*12 + wid;
  bool valid = (r32 < 940);
  int4 zi; zi.x=0; zi.y=0; zi.z=0; zi.w=0;
  const int4* bpr = ((const int4*)rho_f) + (r32*19)*64 + lane;
  int4 bfr[19];
  #pragma unroll
  for (int ks=0;ks<19;ks++) bfr[ks] = valid ? bpr[ks*64] : zi;
  int v = vb*384 + wid*32 + (lane&31);
  bool vok = (v < 30000);
  float local = 0.f;
  for (int t = tg*30; t < tg*30+30; t++){
    int d0 = dstart[t], d1 = dstart[t+1];
    if (d0 == d1) continue;
    v16f acc0, acc1;
    #pragma unroll
    for (int i=0;i<16;i++){ acc0[i]=0.f; acc1[i]=0.f; }
    const int4* ap = ((const int4*)alpha_f) + (t*38)*64 + lane;
    #pragma unroll
    for (int ks=0;ks<19;ks++){
      I4BF a0f, a1f, bf;
      a0f.i = ap[ks*64];
      a1f.i = ap[(19+ks)*64];
      bf.i  = bfr[ks];
      acc0 = __builtin_amdgcn_mfma_f32_32x32x16_bf16(a0f.s, bf.s, acc0, 0,0,0);
      acc1 = __builtin_amdgcn_mfma_f32_32x32x16_bf16(a1f.s, bf.s, acc1, 0,0,0);
    }
    // normalize in place: P = exp(logit - M_k) * iS_k
    const float* MgT = Mg + t*50;
    const float* iST = iSg + t*50;
    #pragma unroll
    for (int r=0;r<16;r++){
      int kl = (r&3) + ((r>>2)<<3) + (h<<2);   // 0..31
      acc0[r] = __expf(acc0[r] - MgT[kl]) * iST[kl];
      int k1 = 32 + kl;
      acc1[r] = (k1 < 50) ? __expf(acc1[r] - MgT[k1]) * iST[k1] : 0.f;
    }
    for (int di=d0; di<d1; di++){
      int b = dlist[di];
      const float* th = &thS[b*52];
      float part = 0.f;
      #pragma unroll
      for (int r=0;r<16;r++){
        int kl = (r&3) + ((r>>2)<<3) + (h<<2);
        part = fmaf(acc0[r], th[kl], part);
        int k1 = 32 + kl;
        if (k1 < 50) part = fmaf(acc1[r], th[k1], part);
      }
      part += __shfl_xor(part, 32);
      if (lane < 32 && vok){
        float lg = __logf(part + 1e-6f);
        local = fmaf(-lg, bows[b*30000 + v], local);
      }
    }
  }
  for (int o=1;o<64;o<<=1) local += __shfl_xor(local, o);
  if (lane==0) redL[wid] = local;
  __syncthreads();
  if (TID==0){
    float s = 0.f;
    #pragma unroll
    for (int w2=0; w2<12; w2++) s += redL[w2];
    atomicAdd(acc+3, s);
    int n = __hip_atomic_fetch_add(flags+FG_MF2D, 1, __ATOMIC_ACQ_REL, __HIP_MEMORY_SCOPE_AGENT);
    if (n == 157){
      float coeff = (float)(*nd) / 128.0f;
      float nll = acc[3]*coeff;
      float klth = acc[2]*coeff;
      out[0] = nll + acc[0] + acc[1] + klth;
      out[1] = nll;
      out[2] = acc[0];
      out[3] = acc[1];
      out[4] = klth;
    }
  }
}

extern "C" void kernel_launch(void* const* d_in, const int* in_sizes, int n_in,
                              void* d_out, int out_size, void* d_ws, size_t ws_size,
                              hipStream_t stream) {
  (void)in_sizes; (void)n_in; (void)out_size; (void)ws_size;
  const float* bows  = (const float*)d_in[0];
  const float* nb    = (const float*)d_in[1];
  const int*   times = (const int*)d_in[2];
  const float* rnn   = (const float*)d_in[3];
  const int*   ndocs = (const int*)d_in[4];
  const float* eps_a = (const float*)d_in[5];
  const float* eps_e = (const float*)d_in[6];
  const float* eps_t = (const float*)d_in[7];
  const float* rho   = (const float*)d_in[8];
  const float* mqa   = (const float*)d_in[9];
  const float* lqa   = (const float*)d_in[10];
  const float* W1    = (const float*)d_in[11];
  const float* b1    = (const float*)d_in[12];
  const float* W2    = (const float*)d_in[13];
  const float* b2    = (const float*)d_in[14];
  const float* Wmu_t = (const float*)d_in[15];
  const float* bmu_t = (const float*)d_in[16];
  const float* Wls_t = (const float*)d_in[17];
  const float* bls_t = (const float*)d_in[18];
  const float* Wmap  = (const float*)d_in[19];
  const float* bmap  = (const float*)d_in[20];
  const float* Wih   = (const float*)d_in[21];
  const float* Whh   = (const float*)d_in[22];
  const float* bih   = (const float*)d_in[23];
  const float* bhh   = (const float*)d_in[24];
  const float* Wmu_e = (const float*)d_in[25];
  const float* bmu_e = (const float*)d_in[26];
  const float* Wls_e = (const float*)d_in[27];
  const float* bls_e = (const float*)d_in[28];
  float* out = (float*)d_out;

  float* p = (float*)d_ws;
  float* acc    = p; p += 8;
  unsigned short* rho_f   = (unsigned short*)p; p += 4572160;  // 940*19*64 int4
  unsigned short* alpha_f = (unsigned short*)p; p += 583680;   // 60*2*19*64 int4
  float* alphas = p; p += 900000;
  float* im     = p; p += 12000;
  float* out0   = p; p += 12000;
  float* out1   = p; p += 12000;
  float* out2   = p; p += 12000;
  float* pre0   = p; p += 48000;
  float* pre1   = p; p += 48000;
  float* pre2   = p; p += 48000;
  float* etas   = p; p += 3000;
  float* h1     = p; p += 102400;
  float* h2     = p; p += 102400;
  float* muth   = p; p += 6400;
  float* lsth   = p; p += 6400;
  float* theta  = p; p += 6400;
  float* Mp     = p; p += 3000*NVB2;
  float* Sp     = p; p += 3000*NVB2;
  float* Mg     = p; p += 3000;
  float* iSg    = p; p += 3000;
  int*   flags  = (int*)p; p += 256;

  k_zero<<<1,256,0,stream>>>(acc, flags);
  (void)hipMemsetAsync(h1, 0, 102400*sizeof(float), stream);
  k_alphakl<<<3516,256,0,stream>>>(mqa, lqa, eps_a, alphas, acc);
  k_prep_alpha<<<570,256,0,stream>>>(alphas, alpha_f);
  k_prep_rho<<<4465,256,0,stream>>>(rho, rho_f);
  k_iminit<<<47,256,0,stream>>>(im, bmap);
  k_imgemm<<<dim3(7,60),256,0,stream>>>(rnn, Wmap, im);
  k_pregates<<<dim3(60,4),256,0,stream>>>(im, Wih, bih, bhh, pre0);

  // mega: 6 pipe + 16 h1eta + 12 msred + 316 mf1 + 160 h1 = 510 blocks
  k_mega<<<510,768,0,stream>>>(pre0, Whh, Wih, bih, bhh, out0, out1, out2,
                               pre1, pre2, flags,
                               Wmu_e, bmu_e, Wls_e, bls_e, eps_e, etas, acc,
                               rho_f, alpha_f, Mp, Sp,
                               nb, W1, b1, h1, times, Mg, iSg);

  k_h2<<<dim3(4,13),256,0,stream>>>(h1, W2, b2, h2);
  k_muls<<<128,128,0,stream>>>(h2, Wmu_t, bmu_t, Wls_t, bls_t, muth, lsth);
  k_theta<<<128,64,0,stream>>>(muth, lsth, etas, times, eps_t, theta, acc);
  k_mf2n<<<158,768,0,stream>>>(rho_f, alpha_f, Mg, iSg, theta, times, bows, acc,
                               ndocs, out, flags);
}

// Round 6
// 1345.372 us; speedup vs baseline: 1.2544x; 1.1165x over previous
//
#include <hip/hip_runtime.h>
#include <hip/hip_fp16.h>
#include <math.h>

#define TID ((int)threadIdx.x)

// dims: V=30000 K=50 E=300 T=60 B=128 TH=800 H=200 L=3
// mega-mf1: NVB2=79 v-blocks of 384 rows x 4 tg; mf2n: 79 vb x 2 tg, 768 thr
#define NVB2 79

// flag indices
#define FG_S01   0
#define FG_S12   32
#define FG_S23   64
#define FG_S34   96
#define FG_S45   128
#define FG_ETAT  160
#define FG_MF1D  192
#define FG_MF2D  212

static __device__ __forceinline__ float sigf(float x){ return 1.f/(1.f+__expf(-x)); }
static __device__ __forceinline__ float tanhfast(float x){
  float t = fminf(fmaxf(x,-15.f),15.f);
  float e = __expf(2.f*t);
  return (e-1.f)/(e+1.f);
}

static __device__ __forceinline__ unsigned short f2bf(float f){
  unsigned u = __float_as_uint(f);
  unsigned r = (u + 0x7FFFu + ((u>>16)&1u)) >> 16;
  return (unsigned short)r;
}

typedef short v8ss __attribute__((ext_vector_type(8)));
typedef float v16f __attribute__((ext_vector_type(16)));
typedef _Float16 h2v __attribute__((ext_vector_type(2)));
union I4BF { int4 i; v8ss s; };
union U16B { int4 i; __half2 h2[4]; h2v hv[4]; };

#define REP25(M) M(0) M(1) M(2) M(3) M(4) M(5) M(6) M(7) M(8) M(9) M(10) M(11) \
                 M(12) M(13) M(14) M(15) M(16) M(17) M(18) M(19) M(20) M(21) M(22) M(23) M(24)

// inline f32 -> f16 weight row fragment (8 cols) into named int4 reg
#define DECLWF(n) int4 w##n; { float4 fA = rowF[2*(n)], fB = rowF[2*(n)+1]; U16B u; \
    u.h2[0]=__floats2half2_rn(fA.x,fA.y); u.h2[1]=__floats2half2_rn(fA.z,fA.w); \
    u.h2[2]=__floats2half2_rn(fB.x,fB.y); u.h2[3]=__floats2half2_rn(fB.z,fB.w); w##n=u.i; }

// pin weight fragment into VGPRs (defeat rematerialization / refetch-from-L2)
#define PINW(n) asm volatile("" : "+v"(w##n.x), "+v"(w##n.y), "+v"(w##n.z), "+v"(w##n.w));

// f16 x f16 -> f32 dot pair: 4 v_dot2_f32_f16 per 8-col fragment
#define DOT2(n) { U16B uw, uh; uw.i = w##n; uh.i = hh4[n]; \
    a0 = __builtin_amdgcn_fdot2(uw.hv[0], uh.hv[0], a0, false); \
    a1 = __builtin_amdgcn_fdot2(uw.hv[1], uh.hv[1], a1, false); \
    a2 = __builtin_amdgcn_fdot2(uw.hv[2], uh.hv[2], a2, false); \
    a3 = __builtin_amdgcn_fdot2(uw.hv[3], uh.hv[3], a3, false); }

// ---------------- init ----------------
__global__ void k_zero(float* acc, int* flags){
  if (TID<8) acc[TID]=0.f;
  if (TID<256) flags[TID]=0;
}

// ---------------- alphas + kl_alpha (merged; recompute prev alpha) ----------------
__global__ void k_alphakl(const float* __restrict__ mqa, const float* __restrict__ lqa,
                          const float* __restrict__ eps, float* __restrict__ alphas,
                          float* acc){
  __shared__ float red[256];
  int i = blockIdx.x*256+TID;
  float term = 0.f;
  if (i<900000){
    int t = i/15000, r = i%15000, k = r/300, e = r%300;
    int src = k*18000 + t*300 + e;
    float mu = mqa[src], ls = lqa[src];
    alphas[i] = mu + eps[i]*__expf(0.5f*ls);
    if (t==0){
      term = (__expf(ls)+mu*mu)*(1.0f/(1.0f+1e-6f)) - 1.f - ls;
    } else {
      int sp = src - 300;
      float mup = mqa[sp], lsp = lqa[sp];
      float ap = mup + eps[i-15000]*__expf(0.5f*lsp);
      float d = mu - ap;
      term = (__expf(ls)+d*d)*(1.0f/(0.005f+1e-6f)) - 1.f + logf(0.005f) - ls;
    }
  }
  red[TID]=term; __syncthreads();
  for (int s=128;s>0;s>>=1){ if (TID<s) red[TID]+=red[TID+s]; __syncthreads(); }
  if (TID==0) atomicAdd(acc+0, 0.5f*red[0]);
}

// ---------------- bf16 fragment prep ----------------
__global__ void k_prep_rho(const float* __restrict__ rho, unsigned short* __restrict__ rho_f){
  int tid = blockIdx.x*256+TID;
  if (tid >= 940*19*64) return;
  int lane = tid & 63;
  int F = tid >> 6;
  int kstep = F % 19;
  int r32 = F / 19;
  int v = r32*32 + (lane & 31);
  int e0 = kstep*16 + ((lane>>5)<<3);
  unsigned short u[8];
  #pragma unroll
  for (int j=0;j<8;j++){
    int e = e0 + j;
    float val = (v < 30000 && e < 300) ? rho[v*300 + e] : 0.f;
    u[j] = f2bf(val);
  }
  int4 o;
  o.x = (int)u[0] | ((int)u[1]<<16);
  o.y = (int)u[2] | ((int)u[3]<<16);
  o.z = (int)u[4] | ((int)u[5]<<16);
  o.w = (int)u[6] | ((int)u[7]<<16);
  ((int4*)rho_f)[tid] = o;
}

__global__ void k_prep_alpha(const float* __restrict__ alphas, unsigned short* __restrict__ alpha_f){
  int tid = blockIdx.x*256+TID;
  if (tid >= 60*2*19*64) return;
  int lane = tid & 63;
  int F = tid >> 6;
  int kstep = F % 19;
  int tn = F / 19;
  int nt = tn % 2, t = tn / 2;
  int k = nt*32 + (lane & 31);
  int e0 = kstep*16 + ((lane>>5)<<3);
  unsigned short u[8];
  #pragma unroll
  for (int j=0;j<8;j++){
    int e = e0 + j;
    float val = (k < 50 && e < 300) ? alphas[t*15000 + k*300 + e] : 0.f;
    u[j] = f2bf(val);
  }
  int4 o;
  o.x = (int)u[0] | ((int)u[1]<<16);
  o.y = (int)u[2] | ((int)u[3]<<16);
  o.z = (int)u[4] | ((int)u[5]<<16);
  o.w = (int)u[6] | ((int)u[7]<<16);
  ((int4*)alpha_f)[tid] = o;
}

// ---------------- inp_map = rnn_inp @ Wmap.T + bmap ----------------
__global__ void k_iminit(float* __restrict__ im, const float* __restrict__ bmap){
  int i = blockIdx.x*256+TID; if (i<12000) im[i] = bmap[i%200];
}

__global__ __launch_bounds__(256,2) void k_imgemm(const float* __restrict__ rnn,
        const float* __restrict__ Wmap, float* __restrict__ im){
  __shared__ __align__(16) float Ws[32*500];
  __shared__ __align__(16) float rnS[500];
  int hb = blockIdx.x;       // 0..6
  int kb = blockIdx.y;       // 0..59
  int h0 = hb*32;
  int nh = (h0+32<=200)?32:(200-h0);
  const int kbase = kb*500;
  for (int i=TID; i<nh*125; i+=256){
    int h = i/125, q = i%125;
    *reinterpret_cast<float4*>(&Ws[h*500 + q*4]) =
      *reinterpret_cast<const float4*>(&Wmap[(h0+h)*30000 + kbase + q*4]);
  }
  int h = TID>>3, sub = TID&7;
  bool act = (h < nh);
  __syncthreads();
  for (int t=0;t<60;t++){
    if (TID<125)
      *reinterpret_cast<float4*>(&rnS[TID*4]) =
        *reinterpret_cast<const float4*>(&rnn[t*30000 + kbase + TID*4]);
    __syncthreads();
    float a = 0.f;
    if (act){
      const float2* wp = reinterpret_cast<const float2*>(&Ws[h*500]);
      const float2* rp = reinterpret_cast<const float2*>(rnS);
      for (int k2=sub;k2<250;k2+=8){
        float2 wv=wp[k2], rv=rp[k2];
        a = fmaf(wv.x,rv.x,a); a = fmaf(wv.y,rv.y,a);
      }
    }
    a += __shfl_down(a,4); a += __shfl_down(a,2); a += __shfl_down(a,1);
    if (act && sub==0) atomicAdd(&im[t*200 + h0 + h], a);
    __syncthreads();
  }
}

// ---------------- LSTM pre-gates (layer 0 only) ----------------
__global__ void k_pregates(const float* __restrict__ x, const float* __restrict__ Wih,
                           const float* __restrict__ bih, const float* __restrict__ bhh,
                           float* __restrict__ pre){
  __shared__ float xS[200];
  int t = blockIdx.x;
  if (TID<200) xS[TID] = x[t*200+TID];
  __syncthreads();
  int r = blockIdx.y*256 + TID;
  if (r>=800) return;
  float a = bih[r] + bhh[r];
  const float* wp = Wih + r*200;
  #pragma unroll 4
  for (int c=0;c<200;c++) a = fmaf(wp[c], xS[c], a);
  pre[t*800+r] = a;
}

// ================= MEGA KERNEL =================
// blocks 0-5: LSTM pipe (rec0,gemv1,rec1,gemv2,rec2,eta)
// 6-21: h1eta   22-33: msred   34-349: mf1 (79 vb x 4 tg)   350-509: h1 main GEMM
// Deadlock-safety: waiters depend only on lower-index blocks (pipe chain, h1eta->eta)
// or on free-running blocks that complete and free slots (msred->mf1). Safe even at
// 1 block/CU residency.

template<int SLP>
static __device__ __forceinline__ void pipe_wait(int* flag, int val){
  if (TID==0){
    while (__hip_atomic_load(flag, __ATOMIC_RELAXED, __HIP_MEMORY_SCOPE_AGENT) < val)
      __builtin_amdgcn_s_sleep(SLP);
    (void)__hip_atomic_load(flag, __ATOMIC_ACQUIRE, __HIP_MEMORY_SCOPE_AGENT);
  }
  __syncthreads();
}

static __device__ __forceinline__ void pipe_post(int* flag, int val){
  if (TID==0)
    __hip_atomic_store(flag, val, __ATOMIC_RELEASE, __HIP_MEMORY_SCOPE_AGENT);
}

static __device__ __forceinline__ void post_done(int* ctr){
  __syncthreads();
  if (TID==0)
    __hip_atomic_fetch_add(ctr, 1, __ATOMIC_RELEASE, __HIP_MEMORY_SCOPE_AGENT);
}

// recurrent cell chain: f16 weights pinned in 25 int4 regs; f16 h in LDS; fdot2 dot
static __device__ void lstm_rec(char* sm, const float* __restrict__ pre,
    const float* __restrict__ WhhF, float* __restrict__ out,
    int* inFlag, int* outFlag)
{
  __half* hsH = (__half*)sm;            // 200 h (400B, 16B-aligned)
  float* gsh = (float*)(sm + 512);      // 800 f
  __half* wtH = (__half*)(sm + 4000);   // 6400 h
  for (int i=TID;i<6400;i+=768) wtH[i] = __float2half_rn(WhhF[768*200 + i]);
  const float4* rowF = reinterpret_cast<const float4*>(WhhF + TID*200);
  REP25(DECLWF)
  REP25(PINW)
  float c_reg = 0.f;
  if (TID<200) hsH[TID] = __float2half_rn(0.f);
  int j = TID - 512;
  int trow = (j>=0) ? (j>>3) : 0;
  int tseg = (j>=0) ? (j&7)*25 : 0;
  __syncthreads();
  const int4* hh4 = reinterpret_cast<const int4*>(hsH);
  for (int t=0;t<60;t++){
    if (inFlag) pipe_wait<1>(inFlag, t+1);
    float p = pre[t*800+TID];
    float a0=0.f,a1=0.f,a2=0.f,a3=0.f;
    REP25(DOT2)
    gsh[TID] = a0+a1+a2+a3 + p;
    if (j>=0){
      float pa = 0.f;
      const __half* wt = &wtH[trow*200 + tseg];
      const __half* hp = &hsH[tseg];
      #pragma unroll
      for (int c2=0;c2<25;c2++) pa = fmaf(__half2float(wt[c2]), __half2float(hp[c2]), pa);
      pa += __shfl_down(pa,4); pa += __shfl_down(pa,2); pa += __shfl_down(pa,1);
      if ((j&7)==0) gsh[768+trow] = pa + pre[t*800+768+trow];
    }
    __syncthreads();
    if (TID<200){
      float ii=gsh[TID], ff=gsh[200+TID], gg=gsh[400+TID], oo=gsh[600+TID];
      float c = sigf(ff)*c_reg + sigf(ii)*tanhfast(gg);
      c_reg = c;
      float h = sigf(oo)*tanhfast(c);
      hsH[TID] = __float2half_rn(h);
      out[t*200+TID]=h;
    }
    __syncthreads();
    if (outFlag) pipe_post(outFlag, t+1);
  }
}

// input-gemv stage: pre_l[t] = Wih_l @ out_{l-1}[t] + bih + bhh (f16 x, fdot2)
static __device__ void lstm_gemv(char* sm, const float* __restrict__ xIn,
    const float* __restrict__ WF, const float* __restrict__ bih,
    const float* __restrict__ bhh, float* __restrict__ preOut,
    int* inFlag, int* outFlag)
{
  __half* xH = (__half*)sm;             // 200 h
  __half* wtG = (__half*)(sm + 512);    // 6400 h
  for (int i=TID;i<6400;i+=768) wtG[i] = __float2half_rn(WF[768*200 + i]);
  const float4* rowF = reinterpret_cast<const float4*>(WF + TID*200);
  REP25(DECLWF)
  REP25(PINW)
  float bb = bih[TID] + bhh[TID];
  int j = TID - 512;
  int trow = (j>=0) ? (j>>3) : 0;
  int tseg = (j>=0) ? (j&7)*25 : 0;
  float bbT = 0.f;
  if (j>=0 && (j&7)==0) bbT = bih[768+trow] + bhh[768+trow];
  const int4* hh4 = reinterpret_cast<const int4*>(xH);
  for (int t=0;t<60;t++){
    pipe_wait<1>(inFlag, t+1);
    if (TID<200) xH[TID] = __float2half_rn(xIn[t*200+TID]);
    __syncthreads();
    float a0=0.f,a1=0.f,a2=0.f,a3=0.f;
    REP25(DOT2)
    preOut[t*800+TID] = a0+a1+a2+a3 + bb;
    if (j>=0){
      float pa = 0.f;
      const __half* wt = &wtG[trow*200 + tseg];
      const __half* hp = &xH[tseg];
      #pragma unroll
      for (int c2=0;c2<25;c2++) pa = fmaf(__half2float(wt[c2]), __half2float(hp[c2]), pa);
      pa += __shfl_down(pa,4); pa += __shfl_down(pa,2); pa += __shfl_down(pa,1);
      if ((j&7)==0) preOut[t*800+768+trow] = pa + bbT;
    }
    __syncthreads();
    pipe_post(outFlag, t+1);
  }
}

// eta chain as 6th pipeline stage; posts per-t flag for h1eta consumers
static __device__ void eta_stage(char* sm, const float* __restrict__ outF,
    const float* __restrict__ Wmu, const float* __restrict__ bmu,
    const float* __restrict__ Wls, const float* __restrict__ bls,
    const float* __restrict__ eps, float* __restrict__ etas, float* acc,
    int* inFlag, int* etaT)
{
  __half* wS = (__half*)sm;                 // 100*254 h = 50800 B
  float* inp = (float*)(sm + 50816);        // 256 f
  float* pt  = (float*)(sm + 51840);        // 200 f
  float* muS = (float*)(sm + 52640);        // 64 f
  float* lsS = (float*)(sm + 52896);        // 64 f
  for (int i=TID;i<12500;i+=768) wS[(i/250)*254 + (i%250)] = __float2half_rn(Wmu[i]);
  for (int i=TID;i<12500;i+=768) wS[(50+i/250)*254 + (i%250)] = __float2half_rn(Wls[i]);
  if (TID<50) inp[200+TID]=0.f;
  const float LOGD = logf(0.005f);
  float kacc = 0.f;
  __syncthreads();
  for (int t=0;t<60;t++){
    pipe_wait<1>(inFlag, t+1);
    if (TID<200) inp[TID] = outF[t*200+TID];
    __syncthreads();
    if (TID<200){
      int rr = TID%100, hf = TID/100;
      const __half* wp = &wS[rr*254 + hf*125];
      const float* ip = &inp[hf*125];
      float s=0.f;
      for (int c=0;c<125;c++) s = fmaf(__half2float(wp[c]), ip[c], s);
      pt[TID]=s;
    }
    __syncthreads();
    if (TID<100){
      float v = pt[TID]+pt[TID+100];
      if (TID<50) muS[TID] = v + bmu[TID];
      else lsS[TID-50] = v + bls[TID-50];
    }
    __syncthreads();
    if (TID<64){
      float term=0.f;
      if (TID<50){
        float mu=muS[TID], ls=lsS[TID], ep=inp[200+TID];
        if (t==0) term = (__expf(ls)+mu*mu)*(1.0f/(1.0f+1e-6f)) - 1.f - ls;
        else { float d=mu-ep; term = (__expf(ls)+d*d)*(1.0f/(0.005f+1e-6f)) - 1.f + LOGD - ls; }
        float et = mu + eps[t*50+TID]*__expf(0.5f*ls);
        etas[t*50+TID]=et;
        inp[200+TID]=et;
      }
      for (int o=32;o>0;o>>=1) term += __shfl_down(term,o);
      if (TID==0) kacc += 0.5f*term;
    }
    __syncthreads();
    pipe_post(etaT, t+1);
  }
  if (TID==0) atomicAdd(acc+1, kacc);
}

// MFMA beta pass 1: 12 waves = 384 v-rows per block, 15 t per block
static __device__ void mf1_block(char* sm, int vb, int tg,
    const unsigned short* __restrict__ rho_f, const unsigned short* __restrict__ alpha_f,
    float* __restrict__ Mp, float* __restrict__ Sp, int* mf1d)
{
  float* redM = (float*)sm;            // 12*64 f
  float* redS = (float*)(sm + 3072);   // 12*64 f
  int wid = TID>>6, lane = TID&63;
  int r32 = vb*12 + wid;
  bool valid = (r32 < 940);
  int4 zi; zi.x=0; zi.y=0; zi.z=0; zi.w=0;
  const int4* ap = ((const int4*)rho_f) + (r32*19)*64 + lane;
  int4 a[19];
  #pragma unroll
  for (int ks=0;ks<19;ks++) a[ks] = valid ? ap[ks*64] : zi;
  #pragma unroll
  for (int ks=0;ks<19;ks++)
    asm volatile("" : "+v"(a[ks].x), "+v"(a[ks].y), "+v"(a[ks].z), "+v"(a[ks].w));
  int rowbase = vb*384 + wid*32 + ((lane>>5)<<2);
  for (int t = tg*15; t < tg*15+15; t++){
    v16f acc0, acc1;
    #pragma unroll
    for (int i=0;i<16;i++){ acc0[i]=0.f; acc1[i]=0.f; }
    const int4* bp = ((const int4*)alpha_f) + (t*38)*64 + lane;
    #pragma unroll
    for (int ks=0;ks<19;ks++){
      I4BF av, b0, b1;
      av.i = a[ks];
      b0.i = bp[ks*64];
      b1.i = bp[(19+ks)*64];
      acc0 = __builtin_amdgcn_mfma_f32_32x32x16_bf16(av.s, b0.s, acc0, 0,0,0);
      acc1 = __builtin_amdgcn_mfma_f32_32x32x16_bf16(av.s, b1.s, acc1, 0,0,0);
    }
    float m0=-INFINITY, m1=-INFINITY;
    #pragma unroll
    for (int r=0;r<16;r++){
      int v = rowbase + (r&3) + ((r>>2)<<3);
      if (v < 30000){ m0 = fmaxf(m0, acc0[r]); m1 = fmaxf(m1, acc1[r]); }
    }
    m0 = fmaxf(m0, __shfl_xor(m0, 32));
    m1 = fmaxf(m1, __shfl_xor(m1, 32));
    float s0=0.f, s1=0.f;
    #pragma unroll
    for (int r=0;r<16;r++){
      int v = rowbase + (r&3) + ((r>>2)<<3);
      if (v < 30000){ s0 += __expf(acc0[r]-m0); s1 += __expf(acc1[r]-m1); }
    }
    s0 += __shfl_xor(s0, 32);
    s1 += __shfl_xor(s1, 32);
    if (lane < 32){
      redM[wid*64+lane] = m0; redM[wid*64+lane+32] = m1;
      redS[wid*64+lane] = s0; redS[wid*64+lane+32] = s1;
    }
    __syncthreads();
    if (TID < 50){
      float M = redM[TID];
      #pragma unroll
      for (int w2=1; w2<12; w2++) M = fmaxf(M, redM[w2*64+TID]);
      float S = 0.f;
      #pragma unroll
      for (int w2=0; w2<12; w2++){
        float mw = redM[w2*64+TID];
        if (mw > -INFINITY) S += redS[w2*64+TID] * __expf(mw - M);
      }
      Mp[(t*50+TID)*NVB2 + vb] = M;
      Sp[(t*50+TID)*NVB2 + vb] = S;
    }
    __syncthreads();
  }
  post_done(mf1d);
}

// h1 main GEMM (k<30000 only): 3 rt-tiles share one A-tile
static __device__ void h1_block(char* sm, int rtg, int sp,
    const float* __restrict__ nb, const float* __restrict__ W1,
    float* __restrict__ h1)
{
  float* As = (float*)sm;               // 16*132 f
  float* WsAll = (float*)(sm + 8448);   // 3 * 16*68 f
  int sub = TID>>8, l = TID&255;
  int rt = rtg*3 + sub;                 // 0..14 (rows >=800 masked)
  float* Ws = WsAll + sub*(16*68);
  int kbeg = sp*940;
  int kend = kbeg+940; if (kend>30000) kend=30000;
  int b0 = (l%32)*4, r0 = (l/32)*8;
  float acc[32];
  #pragma unroll
  for (int jj=0;jj<32;jj++) acc[jj]=0.f;
  for (int kb=kbeg; kb<kend; kb+=16){
    __syncthreads();
    for (int i=TID;i<2048;i+=768){
      int b=i>>4, kk=i&15, kg=kb+kk;
      As[kk*132+b] = (kg<kend) ? nb[b*30000+kg] : 0.f;
    }
    for (int i=l;i<1024;i+=256){
      int r=i>>4, kk=i&15, kg=kb+kk, rg=rt*64+r;
      Ws[kk*68+r] = (kg<kend && rg<800) ? W1[rg*30050+kg] : 0.f;
    }
    __syncthreads();
    #pragma unroll
    for (int kk=0;kk<16;kk++){
      float4 a4 = *reinterpret_cast<const float4*>(&As[kk*132+b0]);
      float4 w4 = *reinterpret_cast<const float4*>(&Ws[kk*68+r0]);
      float4 w5 = *reinterpret_cast<const float4*>(&Ws[kk*68+r0+4]);
      float aa[4]={a4.x,a4.y,a4.z,a4.w};
      float ww[8]={w4.x,w4.y,w4.z,w4.w,w5.x,w5.y,w5.z,w5.w};
      #pragma unroll
      for (int j=0;j<4;j++)
        #pragma unroll
        for (int i2=0;i2<8;i2++) acc[j*8+i2] = fmaf(aa[j], ww[i2], acc[j*8+i2]);
    }
  }
  #pragma unroll
  for (int j=0;j<4;j++){
    int b=b0+j;
    #pragma unroll
    for (int i2=0;i2<8;i2++){
      int rg = rt*64+r0+i2;
      if (rg<800) atomicAdd(&h1[b*800+rg], acc[j*8+i2]);
    }
  }
}

// reduce Mp/Sp partials -> Mg, 1/S (12 blocks x 12 waves)
static __device__ void msred_role(int blk, const float* __restrict__ Mp,
    const float* __restrict__ Sp, float* __restrict__ Mg, float* __restrict__ iSg,
    int* mf1d)
{
  pipe_wait<16>(mf1d, 316);
  int w = TID>>6, lane = TID&63;
  for (int row = blk*12 + w; row < 3000; row += 144){
    float m0 = (lane < NVB2) ? Mp[row*NVB2 + lane] : -INFINITY;
    float m1 = (64+lane < NVB2) ? Mp[row*NVB2 + 64 + lane] : -INFINITY;
    float s0 = (lane < NVB2) ? Sp[row*NVB2 + lane] : 0.f;
    float s1 = (64+lane < NVB2) ? Sp[row*NVB2 + 64 + lane] : 0.f;
    float mm = fmaxf(m0, m1);
    for (int o=32;o>0;o>>=1) mm = fmaxf(mm, __shfl_xor(mm,o));
    float e = 0.f;
    if (m0 > -INFINITY) e += s0*__expf(m0-mm);
    if (m1 > -INFINITY) e += s1*__expf(m1-mm);
    for (int o=32;o>0;o>>=1) e += __shfl_xor(e,o);
    if (lane==0){ Mg[row]=mm; iSg[row]=1.f/e; }
  }
}

// eta columns of h1 + bias (per-doc overlap with eta pipeline)
static __device__ void h1eta_role(char* sm, int blk, const float* __restrict__ etas,
    const int* __restrict__ times, const float* __restrict__ W1,
    const float* __restrict__ b1, float* __restrict__ h1, int* etaT)
{
  float* eS = (float*)sm;  // 64 f
  for (int d=0; d<8; d++){
    int b = blk*8 + d;
    int tb = times[b];
    pipe_wait<4>(etaT, tb+1);
    if (TID<50) eS[TID] = etas[tb*50+TID];
    __syncthreads();
    for (int r=TID; r<800; r+=768){
      const float* wp = W1 + r*30050 + 30000;
      float a2 = b1[r];
      #pragma unroll 10
      for (int c=0;c<50;c++) a2 = fmaf(wp[c], eS[c], a2);
      atomicAdd(&h1[b*800+r], a2);
    }
    __syncthreads();
  }
}

__global__ __launch_bounds__(768) void k_mega(
    const float* __restrict__ pre0, const float* __restrict__ Whh,
    const float* __restrict__ Wih, const float* __restrict__ bih,
    const float* __restrict__ bhh, float* __restrict__ out0,
    float* __restrict__ out1, float* __restrict__ out2,
    float* __restrict__ pre1, float* __restrict__ pre2, int* __restrict__ flags,
    const float* __restrict__ Wmu_e, const float* __restrict__ bmu_e,
    const float* __restrict__ Wls_e, const float* __restrict__ bls_e,
    const float* __restrict__ eps_e, float* __restrict__ etas, float* acc,
    const unsigned short* __restrict__ rho_f, const unsigned short* __restrict__ alpha_f,
    float* __restrict__ Mp, float* __restrict__ Sp,
    const float* __restrict__ nb, const float* __restrict__ W1,
    const float* __restrict__ b1, float* __restrict__ h1,
    const int* __restrict__ times, float* __restrict__ Mg, float* __restrict__ iSg)
{
  __shared__ __align__(16) unsigned char smem[53248];
  char* sm = (char*)smem;
  int bid = blockIdx.x;
  if (bid==0)      lstm_rec (sm, pre0, Whh,        out0, nullptr,   flags+FG_S01);
  else if (bid==1) lstm_gemv(sm, out0, Wih+160000, bih+800,  bhh+800,  pre1, flags+FG_S01, flags+FG_S12);
  else if (bid==2) lstm_rec (sm, pre1, Whh+160000, out1, flags+FG_S12, flags+FG_S23);
  else if (bid==3) lstm_gemv(sm, out1, Wih+320000, bih+1600, bhh+1600, pre2, flags+FG_S23, flags+FG_S34);
  else if (bid==4) lstm_rec (sm, pre2, Whh+320000, out2, flags+FG_S34, flags+FG_S45);
  else if (bid==5) eta_stage(sm, out2, Wmu_e, bmu_e, Wls_e, bls_e, eps_e, etas, acc,
                             flags+FG_S45, flags+FG_ETAT);
  else if (bid<22){ h1eta_role(sm, bid-6, etas, times, W1, b1, h1, flags+FG_ETAT); }
  else if (bid<34){ msred_role(bid-22, Mp, Sp, Mg, iSg, flags+FG_MF1D); }
  else if (bid<350){ int i=bid-34;  mf1_block(sm, i>>2, i&3, rho_f, alpha_f, Mp, Sp, flags+FG_MF1D); }
  else             { int j=bid-350; h1_block(sm, j>>5, j&31, nb, W1, h1); }
}

// ---------------- h2 = relu(relu(h1) @ W2.T + b2), tiled 32x64 ----------------
__global__ __launch_bounds__(256) void k_h2(const float* __restrict__ h1,
        const float* __restrict__ W2, const float* __restrict__ b2,
        float* __restrict__ h2){
  __shared__ __align__(16) float As[16*33];
  __shared__ __align__(16) float Ws[16*68];
  int bt = blockIdx.x;  // 0..3
  int rt = blockIdx.y;  // 0..12
  int b0 = (TID%16)*2, r0 = (TID/16)*4;
  float acc[8] = {0,0,0,0,0,0,0,0};
  for (int kb=0; kb<800; kb+=16){
    __syncthreads();
    for (int i=TID;i<512;i+=256){
      int b=i>>4, k=i&15;
      As[k*33+b] = fmaxf(h1[(bt*32+b)*800 + kb + k], 0.f);
    }
    for (int i=TID;i<1024;i+=256){
      int r=i>>4, k=i&15; int rg = rt*64+r;
      Ws[k*68+r] = (rg<800) ? W2[rg*800 + kb + k] : 0.f;
    }
    __syncthreads();
    #pragma unroll
    for (int k=0;k<16;k++){
      float a0=As[k*33+b0], a1=As[k*33+b0+1];
      float4 w4 = *reinterpret_cast<const float4*>(&Ws[k*68+r0]);
      acc[0]=fmaf(a0,w4.x,acc[0]); acc[1]=fmaf(a0,w4.y,acc[1]);
      acc[2]=fmaf(a0,w4.z,acc[2]); acc[3]=fmaf(a0,w4.w,acc[3]);
      acc[4]=fmaf(a1,w4.x,acc[4]); acc[5]=fmaf(a1,w4.y,acc[5]);
      acc[6]=fmaf(a1,w4.z,acc[6]); acc[7]=fmaf(a1,w4.w,acc[7]);
    }
  }
  #pragma unroll
  for (int jj=0;jj<2;jj++){
    int b = bt*32 + b0 + jj;
    #pragma unroll
    for (int i2=0;i2<4;i2++){
      int rg = rt*64 + r0 + i2;
      if (rg<800) h2[b*800+rg] = fmaxf(acc[jj*4+i2] + b2[rg], 0.f);
    }
  }
}

// ---------------- mu_th / ls_th ----------------
__global__ void k_muls(const float* __restrict__ h2, const float* __restrict__ Wmu,
                       const float* __restrict__ bmu, const float* __restrict__ Wls,
                       const float* __restrict__ bls, float* __restrict__ muth,
                       float* __restrict__ lsth){
  __shared__ float hS[800];
  int b = blockIdx.x;
  for (int i=TID;i<800;i+=128) hS[i] = h2[b*800+i];
  __syncthreads();
  if (TID<50){
    float a = bmu[TID];
    const float* wp = Wmu + TID*800;
    #pragma unroll 4
    for (int c=0;c<800;c++) a = fmaf(wp[c], hS[c], a);
    muth[b*50+TID]=a;
  } else if (TID>=64 && TID<114){
    int r = TID-64;
    float a = bls[r];
    const float* wp = Wls + r*800;
    #pragma unroll 4
    for (int c=0;c<800;c++) a = fmaf(wp[c], hS[c], a);
    lsth[b*50+r]=a;
  }
}

// ---------------- theta + kl_theta ----------------
__global__ void k_theta(const float* __restrict__ muth, const float* __restrict__ lsth,
                        const float* __restrict__ etas, const int* __restrict__ times,
                        const float* __restrict__ epsth, float* __restrict__ theta,
                        float* acc){
  int b = blockIdx.x, k = TID;
  bool a = k<50;
  int tb = times[b];
  float mu=0.f, ls=0.f, etd=0.f, z=-INFINITY;
  if (a){
    mu = muth[b*50+k]; ls = lsth[b*50+k]; etd = etas[tb*50+k];
    z = mu + epsth[b*50+k]*__expf(0.5f*ls);
  }
  float m=z;
  for (int o=32;o>0;o>>=1) m = fmaxf(m, __shfl_xor(m,o));
  float e = a ? __expf(z-m) : 0.f;
  float s = e;
  for (int o=32;o>0;o>>=1) s += __shfl_xor(s,o);
  if (a) theta[b*50+k] = e/s;
  float term = a ? ((__expf(ls)+(mu-etd)*(mu-etd))*(1.0f/(1.0f+1e-6f)) - 1.f - ls) : 0.f;
  for (int o=32;o>0;o>>=1) term += __shfl_xor(term,o);
  if (TID==0) atomicAdd(acc+2, 0.5f*term);
}

// ---------------- MFMA beta pass 2, transposed: D[k][v], v = lane&31 ----------------
__global__ __launch_bounds__(768) void k_mf2n(const unsigned short* __restrict__ rho_f,
        const unsigned short* __restrict__ alpha_f,
        const float* __restrict__ Mg, const float* __restrict__ iSg,
        const float* __restrict__ theta, const int* __restrict__ times,
        const float* __restrict__ bows, float* acc,
        const int* __restrict__ nd, float* __restrict__ out, int* __restrict__ flags){
  __shared__ float thS[128*52];
  __shared__ int tSd[128];
  __shared__ int dlist[128];
  __shared__ int dstart[61];
  __shared__ float redL[12];
  int vb = blockIdx.x >> 1;      // 0..78
  int tg = blockIdx.x & 1;       // 0..1
  int wid = TID>>6, lane = TID&63;
  int h = lane>>5;
  for (int i=TID; i<6400; i+=768){ int b=i/50, c=i%50; thS[b*52+c] = theta[i]; }
  if (TID<128) tSd[TID] = times[TID];
  __syncthreads();
  if (TID==0){
    int cnt[60];
    #pragma unroll
    for (int t=0;t<60;t++) cnt[t]=0;
    for (int b=0;b<128;b++) cnt[tSd[b]]++;
    int o=0;
    for (int t=0;t<60;t++){ dstart[t]=o; o+=cnt[t]; cnt[t]=dstart[t]; }
    dstart[60]=o;
    for (int b=0;b<128;b++){ int t=tSd[b]; dlist[cnt[t]++]=b; }
  }
  __syncthreads();
  int r32 = vb*12 + wid;
  bool valid = (r32 < 940);
  int4 zi; zi.x=0; zi.y=0; zi.z=0; zi.w=0;
  const int4* bpr = ((const int4*)rho_f) + (r32*19)*64 + lane;
  int4 bfr[19];
  #pragma unroll
  for (int ks=0;ks<19;ks++) bfr[ks] = valid ? bpr[ks*64] : zi;
  #pragma unroll
  for (int ks=0;ks<19;ks++)
    asm volatile("" : "+v"(bfr[ks].x), "+v"(bfr[ks].y), "+v"(bfr[ks].z), "+v"(bfr[ks].w));
  int v = vb*384 + wid*32 + (lane&31);
  bool vok = (v < 30000);
  float local = 0.f;
  for (int t = tg*30; t < tg*30+30; t++){
    int d0 = dstart[t], d1 = dstart[t+1];
    if (d0 == d1) continue;
    v16f acc0, acc1;
    #pragma unroll
    for (int i=0;i<16;i++){ acc0[i]=0.f; acc1[i]=0.f; }
    const int4* ap = ((const int4*)alpha_f) + (t*38)*64 + lane;
    #pragma unroll
    for (int ks=0;ks<19;ks++){
      I4BF a0f, a1f, bf;
      a0f.i = ap[ks*64];
      a1f.i = ap[(19+ks)*64];
      bf.i  = bfr[ks];
      acc0 = __builtin_amdgcn_mfma_f32_32x32x16_bf16(a0f.s, bf.s, acc0, 0,0,0);
      acc1 = __builtin_amdgcn_mfma_f32_32x32x16_bf16(a1f.s, bf.s, acc1, 0,0,0);
    }
    const float* MgT = Mg + t*50;
    const float* iST = iSg + t*50;
    #pragma unroll
    for (int r=0;r<16;r++){
      int kl = (r&3) + ((r>>2)<<3) + (h<<2);   // 0..31
      acc0[r] = __expf(acc0[r] - MgT[kl]) * iST[kl];
      int k1 = 32 + kl;
      acc1[r] = (k1 < 50) ? __expf(acc1[r] - MgT[k1]) * iST[k1] : 0.f;
    }
    for (int di=d0; di<d1; di++){
      int b = dlist[di];
      const float* th = &thS[b*52];
      float part = 0.f;
      #pragma unroll
      for (int r=0;r<16;r++){
        int kl = (r&3) + ((r>>2)<<3) + (h<<2);
        part = fmaf(acc0[r], th[kl], part);
        int k1 = 32 + kl;
        if (k1 < 50) part = fmaf(acc1[r], th[k1], part);
      }
      part += __shfl_xor(part, 32);
      if (lane < 32 && vok){
        float lg = __logf(part + 1e-6f);
        local = fmaf(-lg, bows[b*30000 + v], local);
      }
    }
  }
  for (int o=1;o<64;o<<=1) local += __shfl_xor(local, o);
  if (lane==0) redL[wid] = local;
  __syncthreads();
  if (TID==0){
    float s = 0.f;
    #pragma unroll
    for (int w2=0; w2<12; w2++) s += redL[w2];
    atomicAdd(acc+3, s);
    int n = __hip_atomic_fetch_add(flags+FG_MF2D, 1, __ATOMIC_ACQ_REL, __HIP_MEMORY_SCOPE_AGENT);
    if (n == 157){
      float coeff = (float)(*nd) / 128.0f;
      float nll = acc[3]*coeff;
      float klth = acc[2]*coeff;
      out[0] = nll + acc[0] + acc[1] + klth;
      out[1] = nll;
      out[2] = acc[0];
      out[3] = acc[1];
      out[4] = klth;
    }
  }
}

extern "C" void kernel_launch(void* const* d_in, const int* in_sizes, int n_in,
                              void* d_out, int out_size, void* d_ws, size_t ws_size,
                              hipStream_t stream) {
  (void)in_sizes; (void)n_in; (void)out_size; (void)ws_size;
  const float* bows  = (const float*)d_in[0];
  const float* nb    = (const float*)d_in[1];
  const int*   times = (const int*)d_in[2];
  const float* rnn   = (const float*)d_in[3];
  const int*   ndocs = (const int*)d_in[4];
  const float* eps_a = (const float*)d_in[5];
  const float* eps_e = (const float*)d_in[6];
  const float* eps_t = (const float*)d_in[7];
  const float* rho   = (const float*)d_in[8];
  const float* mqa   = (const float*)d_in[9];
  const float* lqa   = (const float*)d_in[10];
  const float* W1    = (const float*)d_in[11];
  const float* b1    = (const float*)d_in[12];
  const float* W2    = (const float*)d_in[13];
  const float* b2    = (const float*)d_in[14];
  const float* Wmu_t = (const float*)d_in[15];
  const float* bmu_t = (const float*)d_in[16];
  const float* Wls_t = (const float*)d_in[17];
  const float* bls_t = (const float*)d_in[18];
  const float* Wmap  = (const float*)d_in[19];
  const float* bmap  = (const float*)d_in[20];
  const float* Wih   = (const float*)d_in[21];
  const float* Whh   = (const float*)d_in[22];
  const float* bih   = (const float*)d_in[23];
  const float* bhh   = (const float*)d_in[24];
  const float* Wmu_e = (const float*)d_in[25];
  const float* bmu_e = (const float*)d_in[26];
  const float* Wls_e = (const float*)d_in[27];
  const float* bls_e = (const float*)d_in[28];
  float* out = (float*)d_out;

  float* p = (float*)d_ws;
  float* acc    = p; p += 8;
  unsigned short* rho_f   = (unsigned short*)p; p += 4572160;  // 940*19*64 int4
  unsigned short* alpha_f = (unsigned short*)p; p += 583680;   // 60*2*19*64 int4
  float* alphas = p; p += 900000;
  float* im     = p; p += 12000;
  float* out0   = p; p += 12000;
  float* out1   = p; p += 12000;
  float* out2   = p; p += 12000;
  float* pre0   = p; p += 48000;
  float* pre1   = p; p += 48000;
  float* pre2   = p; p += 48000;
  float* etas   = p; p += 3000;
  float* h1     = p; p += 102400;
  float* h2     = p; p += 102400;
  float* muth   = p; p += 6400;
  float* lsth   = p; p += 6400;
  float* theta  = p; p += 6400;
  float* Mp     = p; p += 3000*NVB2;
  float* Sp     = p; p += 3000*NVB2;
  float* Mg     = p; p += 3000;
  float* iSg    = p; p += 3000;
  int*   flags  = (int*)p; p += 256;

  k_zero<<<1,256,0,stream>>>(acc, flags);
  (void)hipMemsetAsync(h1, 0, 102400*sizeof(float), stream);
  k_alphakl<<<3516,256,0,stream>>>(mqa, lqa, eps_a, alphas, acc);
  k_prep_alpha<<<570,256,0,stream>>>(alphas, alpha_f);
  k_prep_rho<<<4465,256,0,stream>>>(rho, rho_f);
  k_iminit<<<47,256,0,stream>>>(im, bmap);
  k_imgemm<<<dim3(7,60),256,0,stream>>>(rnn, Wmap, im);
  k_pregates<<<dim3(60,4),256,0,stream>>>(im, Wih, bih, bhh, pre0);

  // mega: 6 pipe + 16 h1eta + 12 msred + 316 mf1 + 160 h1 = 510 blocks
  k_mega<<<510,768,0,stream>>>(pre0, Whh, Wih, bih, bhh, out0, out1, out2,
                               pre1, pre2, flags,
                               Wmu_e, bmu_e, Wls_e, bls_e, eps_e, etas, acc,
                               rho_f, alpha_f, Mp, Sp,
                               nb, W1, b1, h1, times, Mg, iSg);

  k_h2<<<dim3(4,13),256,0,stream>>>(h1, W2, b2, h2);
  k_muls<<<128,128,0,stream>>>(h2, Wmu_t, bmu_t, Wls_t, bls_t, muth, lsth);
  k_theta<<<128,64,0,stream>>>(muth, lsth, etas, times, eps_t, theta, acc);
  k_mf2n<<<158,768,0,stream>>>(rho_f, alpha_f, Mg, iSg, theta, times, bows, acc,
                               ndocs, out, flags);
}